// Round 1
// baseline (1101.896 us; speedup 1.0000x reference)
//
#include <hip/hip_runtime.h>
#include <math.h>

#define NS 131072
#define EPSF 1e-8f

// workspace float offsets
#define OFF_RES    0u        // 32*131072 res_raw[rx][t]
#define OFF_H      4194304u  // 32*131072 H[rx][t]
#define OFF_IMP    8388608u  // 16*2048
#define OFF_VG     8421376u  // 8*2048
#define OFF_DW     8437760u  // 131072 deformation ch0 weight
#define OFF_FV     8568832u  // 4*16*128 routed frames
#define OFF_NORM   8577024u  // 32 res sumsq
#define OFF_GSS    8577056u  // 8 gauss sumsq
#define OFF_MIX0   8577064u  // 16
#define OFF_MIX1   8577080u  // 16
#define OFF_GABS   8577096u  // 16
#define OFF_W3     8577112u  // 32*3 stack softmax
#define OFF_PF     8577208u  // 32*26 osc params (gam[6],amp[6],x0[6],infl[6],B1[2])
#define WSF_COUNT  8578040u  // doubles follow: 32*8 (Wd[6], om1[2])

__device__ __forceinline__ float red2pi(double ph) {
  double n = floor(ph * 0.15915494309189535 + 0.5);
  return (float)(ph - n * 6.283185307179586);
}

__device__ __forceinline__ float sigmf(float x) { return 1.0f / (1.0f + expf(-x)); }

// ---------------- K0: dw weights (all blocks) + block0: fv/before, mixes, gains, stack w, osc params
__global__ __launch_bounds__(256) void k0_prep(
    const float* __restrict__ csig, const float* __restrict__ deform,
    const float* __restrict__ ddmp, const float* __restrict__ dmas,
    const float* __restrict__ dten, const float* __restrict__ ddisp,
    const float* __restrict__ damp, const float* __restrict__ infl,
    const float* __restrict__ smix, const float* __restrict__ router,
    const float* __restrict__ lmix, const float* __restrict__ gains,
    float* __restrict__ wsf, double* __restrict__ wsd, float* __restrict__ out)
{
  int tid = threadIdx.x;
  int t = blockIdx.x * 256 + tid;
  { // deformation softmax + linear interp weight for channel 0
    float src = (t + 0.5f) * (1.0f / 1024.0f) - 0.5f;
    src = fminf(fmaxf(src, 0.0f), 127.0f);
    int lo = (int)src;
    int hi = min(lo + 1, 127);
    float w = src - (float)lo;
    float c0l = 1.0f / (1.0f + expf(deform[128 + lo] - (1.0f + deform[lo])));
    float c0h = 1.0f / (1.0f + expf(deform[128 + hi] - (1.0f + deform[hi])));
    wsf[OFF_DW + t] = c0l * (1.0f - w) + c0h * w;
  }
  if (blockIdx.x == 0) {
    for (int idx = tid; idx < 8192; idx += 256) {   // fv = einsum('becf,cr')
      int e = idx >> 11, r = (idx >> 7) & 15, f = idx & 127;
      float s = 0.f;
      for (int c = 0; c < 16; ++c) s += csig[(e * 16 + c) * 128 + f] * router[c * 16 + r];
      wsf[OFF_FV + idx] = s;
      out[524288 + idx] = s;   // 'before' output
    }
    if (tid < 16) {
      int r = tid;
      float l0 = lmix[r * 2], l1 = lmix[r * 2 + 1];
      float m = fmaxf(l0, l1);
      float e0 = expf(l0 - m), e1 = expf(l1 - m), inv = 1.0f / (e0 + e1);
      wsf[OFF_MIX0 + r] = e0 * inv;
      wsf[OFF_MIX1 + r] = e1 * inv;
      wsf[OFF_GABS + r] = fabsf(gains[r]);
    }
    if (tid < 32) {
      int rx = tid, r = rx >> 1, x = rx & 1;
      float a0 = smix[rx * 3], a1 = smix[rx * 3 + 1], a2 = smix[rx * 3 + 2];
      float mm = fmaxf(a0, fmaxf(a1, a2));
      float e0 = expf(a0 - mm), e1 = expf(a1 - mm), e2 = expf(a2 - mm);
      float inv = 1.0f / (e0 + e1 + e2);
      wsf[OFF_W3 + rx * 3 + 0] = e0 * inv;
      wsf[OFF_W3 + rx * 3 + 1] = e1 * inv;
      wsf[OFF_W3 + rx * 3 + 2] = e2 * inv;
      float* pf = wsf + OFF_PF + rx * 26;
      double* pd = wsd + rx * 8;
      for (int ent = 0; ent < 6; ++ent) {
        int b = ent >> 1, o = ent & 1;
        int id = ((b * 2 + o) * 16 + r) * 2 + x;
        float mass = 2.0f * sigmf(dmas[id]);
        float dampg = 30.0f * sigmf(ddmp[id]);
        float gam = dampg / (2.0f * mass);
        double W = exp((double)dten[id] * 2.302585092994046) / (double)mass;
        float x0v = ddisp[id];
        float ampv = damp[id];
        float infv = 0.f;
        if (b == 1) infv = infl[(o * 16 + r) * 2 + x];
        if (b == 2) infv = infl[((2 + o) * 16 + r) * 2 + x];
        pf[ent] = gam; pf[6 + ent] = ampv; pf[12 + ent] = x0v; pf[18 + ent] = infv;
        pd[ent] = W;
        if (b == 0) {
          double om = sqrt(W - (double)gam * (double)gam);
          pd[6 + o] = om;
          pf[24 + o] = (float)((double)gam * (double)x0v / om);
        }
      }
    }
  }
}

// ---------------- K1: damped-harmonic-oscillator chain -> res_raw + sumsq
__global__ __launch_bounds__(256) void k1_dho(const float* __restrict__ wsf,
    const double* __restrict__ wsd, float* __restrict__ res, float* __restrict__ norm_acc)
{
  int rx = blockIdx.y;
  int t = blockIdx.x * 256 + threadIdx.x;
  const float*  pf = wsf + OFF_PF + rx * 26;
  const double* pd = wsd + rx * 8;
  double tt = (double)t * (10.0 / 131071.0);
  float ttf = (float)tt;

  float o1v = 0.f;
#pragma unroll
  for (int o = 0; o < 2; ++o) {
    float gam = pf[o];
    float sn, cn;
    sincosf(red2pi(pd[6 + o] * tt), &sn, &cn);
    o1v += pf[6 + o] * expf(-gam * ttf) * (pf[12 + o] * cn + pf[24 + o] * sn);
  }
  float prev = o1v, o2v = 0.f, o3v = 0.f;
#pragma unroll
  for (int blk = 1; blk < 3; ++blk) {
    float acc = 0.f;
#pragma unroll
    for (int oo = 0; oo < 2; ++oo) {
      int o = blk * 2 + oo;
      float gam = pf[o];
      float p10 = expf(prev * pf[18 + o] * 2.3025851f);          // 10^(delta)
      float rad = (float)(pd[o] * (double)p10) - gam * gam;
      float om = sqrtf(rad);
      float B = gam * pf[12 + o] / om;
      float sn, cn;
      sincosf(red2pi((double)om * tt), &sn, &cn);
      acc += pf[6 + o] * expf(-gam * ttf) * (pf[12 + o] * cn + B * sn);
    }
    if (blk == 1) o2v = acc; else o3v = acc;
    prev = acc;
  }
  const float* w3 = wsf + OFF_W3 + rx * 3;
  float rv = w3[0] * o1v + w3[1] * o2v + w3[2] * o3v;
  res[(size_t)rx * NS + t] = rv;
  float sq = rv * rv;
#pragma unroll
  for (int off = 32; off; off >>= 1) sq += __shfl_down(sq, off, 64);
  if ((threadIdx.x & 63) == 0) atomicAdd(&norm_acc[rx], sq);
}

// ---------------- K2: gamma-pdf gaussian stacks, dirac-shifted, summed over cpd; per-g sumsq
__global__ __launch_bounds__(256) void k2_gauss(
    const float* __restrict__ means, const float* __restrict__ stds,
    const float* __restrict__ amps, const float* __restrict__ pos,
    float* __restrict__ vg, float* __restrict__ gss)
{
  int g = blockIdx.x;
  int tid = threadIdx.x;
  __shared__ float kS[16], rateS[16], logAS[16], aS[16];
  __shared__ int dS[16];
  __shared__ float red[4];
  if (tid < 16) {
    int c = tid, idx = c * 8 + g;
    double m = fabs((double)means[idx]);
    double s = fabs((double)stds[idx]);
    double k = m / (s + 1e-8); k = k * k;
    double rate = m / (s * s + 1e-8);
    double logA = k * log(rate + 1e-8) - lgamma(k);
    kS[c] = (float)k; rateS[c] = (float)rate; logAS[c] = (float)logA;
    aS[c] = fabsf(amps[idx]);
    int d = 0;
    for (int l = 0; l < 11; ++l) {
      float p0 = pos[(idx * 11 + l) * 2], p1 = pos[(idx * 11 + l) * 2 + 1];
      d = d * 2 + (p1 > p0 ? 1 : 0);
    }
    dS[c] = d;
  }
  __syncthreads();
  const float step = (float)((1.0 - 1e-8) / 2047.0);
  float sumsq = 0.f;
  for (int i = tid; i < 2048; i += 256) {
    float v = 0.f;
    for (int c = 0; c < 16; ++c) {
      int mi = i - dS[c];
      if (mi >= 0) {
        float tm = 1e-8f + (float)mi * step;
        float lp = logAS[c] + (kS[c] - 1.0f) * logf(tm) - rateS[c] * tm;
        v += aS[c] * expf(lp);
      }
    }
    vg[g * 2048 + i] = v;
    sumsq += v * v;
  }
#pragma unroll
  for (int off = 32; off; off >>= 1) sumsq += __shfl_down(sumsq, off, 64);
  if ((tid & 63) == 0) red[tid >> 6] = sumsq;
  __syncthreads();
  if (tid == 0) gss[g] = red[0] + red[1] + red[2] + red[3];
}

// ---------------- K3: impulse = overall_amp[c] * sum_g unitnorm(v_g) * noise
__global__ __launch_bounds__(256) void k3_imp(
    const float* __restrict__ vg, const float* __restrict__ gss,
    const float* __restrict__ ovamp, const float* __restrict__ noise,
    float* __restrict__ imp)
{
  int c = blockIdx.y;
  int i = blockIdx.x * 256 + threadIdx.x;
  float S = 0.f;
#pragma unroll
  for (int g = 0; g < 8; ++g) S += vg[g * 2048 + i] / (sqrtf(gss[g]) + EPSF);
  imp[c * 2048 + i] = ovamp[c] * S * noise[c * 2048 + i];
}

// ---------------- K4: H[rx] = (imp[r] (*) unitnorm2(res[rx])) * mix1[r]  -- 2048-tap dense conv
#define SWZ(i) ((i) ^ (((i) >> 5) & 7))
__global__ __launch_bounds__(256) void k4_H(
    const float* __restrict__ res, const float* __restrict__ imp,
    const float* __restrict__ norm_acc, const float* __restrict__ wsf,
    float* __restrict__ H)
{
  int rx = blockIdx.y, r = rx >> 1;
  int t0 = blockIdx.x * 2048;
  __shared__ float impr[2048];
  __shared__ float win[4096];
  for (int idx = threadIdx.x; idx < 4096; idx += 256) {
    int gsrc = t0 - 2047 + idx;
    float v = (gsrc >= 0 && gsrc < NS) ? res[(size_t)rx * NS + gsrc] : 0.f;
    win[SWZ(idx)] = v;
  }
  for (int idx = threadIdx.x; idx < 2048; idx += 256)
    impr[idx] = imp[r * 2048 + 2047 - idx];
  float n1 = sqrtf(norm_acc[rx]);
  float s1 = 1.0f / (n1 + EPSF);
  float n2 = n1 * s1;
  float scale = s1 * (1.0f / (n2 + EPSF)) * wsf[OFF_MIX1 + r];
  __syncthreads();
  int base = threadIdx.x * 8;
  float acc[8] = {0, 0, 0, 0, 0, 0, 0, 0};
  float w[8];
#pragma unroll
  for (int k = 0; k < 8; ++k) w[k] = win[SWZ(base + k)];
  for (int j0 = 0; j0 < 2048; j0 += 8) {
    float im[8];
#pragma unroll
    for (int u = 0; u < 8; ++u) im[u] = impr[j0 + u];
#pragma unroll
    for (int u = 0; u < 8; ++u) {
      float iv = im[u];
#pragma unroll
      for (int k = 0; k < 8; ++k) acc[k] += iv * w[k];
#pragma unroll
      for (int k = 0; k < 7; ++k) w[k] = w[k + 1];
      w[7] = win[SWZ(base + j0 + u + 8)];
    }
  }
  int i0 = t0 + base;
#pragma unroll
  for (int k = 0; k < 8; ++k) H[(size_t)rx * NS + i0 + k] = acc[k] * scale;
}

// ---------------- K5: cs output = sum_e (spikes (*) imp)
__global__ __launch_bounds__(256) void k5_cs(
    const float* __restrict__ imp, const float* __restrict__ fv, float* __restrict__ out)
{
  int r = blockIdx.y;
  int t = blockIdx.x * 256 + threadIdx.x;
  int q = t >> 10, sl = t & 1023;
  float i1 = imp[r * 2048 + sl];
  float i2 = (q >= 1) ? imp[r * 2048 + 1024 + sl] : 0.f;
  float s = 0.f;
#pragma unroll
  for (int e = 0; e < 4; ++e) {
    float f1 = fv[(e * 16 + r) * 128 + q];
    float f2 = (q >= 1) ? fv[(e * 16 + r) * 128 + q - 1] : 0.f;
    s += f1 * i1 + f2 * i2;
  }
  out[532480 + (size_t)r * NS + t] = s;
}

// ---------------- K6: 128-tap stride conv as Toeplitz GEMM + deform mix + tanh reduction
__global__ __launch_bounds__(256) void k6_final(
    const float* __restrict__ H, const float* __restrict__ imp,
    const float* __restrict__ wsf, float* __restrict__ out)
{
  int r = blockIdx.y;
  int sb = blockIdx.x * 32;
  int rm = r & 3, rq = r >> 2;
  __shared__ float __align__(16) Hs[2][128][32];
  __shared__ float fvp[4][256];
  __shared__ float __align__(16) impsh[64];
  int tid = threadIdx.x;
  for (int idx = tid; idx < 8192; idx += 256) {
    int xx = idx >> 12, p = (idx >> 5) & 127, sl = idx & 31;
    Hs[xx][p][sl] = H[(size_t)(r * 2 + xx) * NS + p * 1024 + sb + sl];
  }
  for (int idx = tid; idx < 1024; idx += 256) {
    int e = idx >> 8, k = idx & 255, f = k - 127;
    fvp[e][k] = (f >= 0 && f < 128) ? wsf[OFF_FV + (e * 16 + r) * 128 + f] : 0.f;
  }
  if (tid < 32) impsh[tid] = imp[r * 2048 + sb + tid];
  else if (tid < 64) impsh[tid] = imp[r * 2048 + 1024 + sb + (tid - 32)];
  __syncthreads();
  int ts = tid & 7, tq = tid >> 3;            // 8 s-groups x 32 q-groups
  const float* dwg = wsf + OFF_DW;
  float d0w[4][4];
#pragma unroll
  for (int i = 0; i < 4; ++i) {
    int q = tq * 4 + i;
    const float4 dv = *(const float4*)&dwg[q * 1024 + sb + ts * 4];
    d0w[i][0] = dv.x; d0w[i][1] = dv.y; d0w[i][2] = dv.z; d0w[i][3] = dv.w;
  }
  float mix0r = wsf[OFF_MIX0 + r];
  const float4 impA = *(const float4*)&impsh[ts * 4];
  const float4 impB = *(const float4*)&impsh[32 + ts * 4];
  float tansum[4][4] = {};
  for (int e = 0; e < 4; ++e) {
    float acc0[4][4] = {}, acc1[4][4] = {};
    for (int p = 0; p < 128; ++p) {
      const float4 b0 = *(const float4*)&Hs[0][p][ts * 4];
      const float4 b1 = *(const float4*)&Hs[1][p][ts * 4];
      float a[4];
#pragma unroll
      for (int i = 0; i < 4; ++i) a[i] = fvp[e][127 + tq * 4 + i - p];
#pragma unroll
      for (int i = 0; i < 4; ++i) {
        acc0[i][0] += a[i] * b0.x; acc0[i][1] += a[i] * b0.y;
        acc0[i][2] += a[i] * b0.z; acc0[i][3] += a[i] * b0.w;
        acc1[i][0] += a[i] * b1.x; acc1[i][1] += a[i] * b1.y;
        acc1[i][2] += a[i] * b1.z; acc1[i][3] += a[i] * b1.w;
      }
    }
    float ge = wsf[OFF_GABS + 4 * e + rq];
#pragma unroll
    for (int i = 0; i < 4; ++i) {
      int q = tq * 4 + i;
      float fq = fvp[e][127 + q], fqm = fvp[e][126 + q];
      float rsv[4] = { fq * impA.x + fqm * impB.x, fq * impA.y + fqm * impB.y,
                       fq * impA.z + fqm * impB.z, fq * impA.w + fqm * impB.w };
#pragma unroll
      for (int j = 0; j < 4; ++j) {
        float d0 = d0w[i][j];
        float conv = d0 * acc0[i][j] + (1.0f - d0) * acc1[i][j];
        float xm = mix0r * rsv[j] + conv;
        tansum[i][j] += tanhf(xm * ge);
      }
    }
  }
#pragma unroll
  for (int i = 0; i < 4; ++i) {
    int q = tq * 4 + i;
#pragma unroll
    for (int j = 0; j < 4; ++j) {
      int t = q * 1024 + sb + ts * 4 + j;
      atomicAdd(&out[(size_t)rm * NS + t], tansum[i][j]);
    }
  }
}

extern "C" void kernel_launch(void* const* d_in, const int* in_sizes, int n_in,
                              void* d_out, int out_size, void* d_ws, size_t ws_size,
                              hipStream_t stream) {
  const float* csig   = (const float*)d_in[0];
  const float* deform = (const float*)d_in[1];
  const float* aem    = (const float*)d_in[2];
  const float* aes    = (const float*)d_in[3];
  const float* aea    = (const float*)d_in[4];
  const float* aep    = (const float*)d_in[5];
  const float* aeo    = (const float*)d_in[6];
  const float* ddmp   = (const float*)d_in[7];
  const float* dmas   = (const float*)d_in[8];
  const float* dten   = (const float*)d_in[9];
  const float* ddisp  = (const float*)d_in[10];
  const float* damp   = (const float*)d_in[11];
  const float* infl   = (const float*)d_in[12];
  const float* smix   = (const float*)d_in[13];
  const float* router = (const float*)d_in[14];
  const float* lmix   = (const float*)d_in[15];
  const float* gains  = (const float*)d_in[16];
  const float* anoise = (const float*)d_in[17];

  float*  wsf = (float*)d_ws;
  double* wsd = (double*)((char*)d_ws + (size_t)WSF_COUNT * 4);
  float*  out = (float*)d_out;

  // zero the atomically-accumulated regions
  hipMemsetAsync(d_out, 0, (size_t)524288 * 4, stream);
  hipMemsetAsync(wsf + OFF_NORM, 0, 32 * 4, stream);

  k0_prep<<<512, 256, 0, stream>>>(csig, deform, ddmp, dmas, dten, ddisp, damp,
                                   infl, smix, router, lmix, gains, wsf, wsd, out);
  k1_dho<<<dim3(512, 32), 256, 0, stream>>>(wsf, wsd, wsf + OFF_RES, wsf + OFF_NORM);
  k2_gauss<<<8, 256, 0, stream>>>(aem, aes, aea, aep, wsf + OFF_VG, wsf + OFF_GSS);
  k3_imp<<<dim3(8, 16), 256, 0, stream>>>(wsf + OFF_VG, wsf + OFF_GSS, aeo, anoise,
                                          wsf + OFF_IMP);
  k4_H<<<dim3(64, 32), 256, 0, stream>>>(wsf + OFF_RES, wsf + OFF_IMP,
                                         wsf + OFF_NORM, wsf, wsf + OFF_H);
  k5_cs<<<dim3(512, 16), 256, 0, stream>>>(wsf + OFF_IMP, wsf + OFF_FV, out);
  k6_final<<<dim3(32, 16), 256, 0, stream>>>(wsf + OFF_H, wsf + OFF_IMP, wsf, out);
}

// Round 2
// 531.769 us; speedup vs baseline: 2.0721x; 2.0721x over previous
//
#include <hip/hip_runtime.h>
#include <math.h>

#define NS 131072
#define EPSF 1e-8f

// workspace float offsets
#define OFF_RES    0u        // 32*131072 res_raw[rx][t]
#define OFF_H      4194304u  // 32*131072 H[rx][t]
#define OFF_IMP    8388608u  // 16*2048
#define OFF_VG     8421376u  // 8*2048
#define OFF_DW     8437760u  // 131072 deformation ch0 weight
#define OFF_FV     8568832u  // 4*16*128 routed frames
#define OFF_NORM   8577024u  // 32 res sumsq
#define OFF_GSS    8577056u  // 8 gauss sumsq
#define OFF_MIX0   8577064u  // 16
#define OFF_MIX1   8577080u  // 16
#define OFF_GABS   8577096u  // 16
#define OFF_W3     8577112u  // 32*3 stack softmax
#define OFF_PF     8577208u  // 32*26 osc params (gam[6],amp[6],x0[6],infl[6],B1[2])
#define WSF_COUNT  8578040u  // doubles follow: 32*8 (Wd[6], om1[2]) = 512 floats
#define OFF_PART   8578560u  // 32*512 per-block norm partials

__device__ __forceinline__ float red2pi(double ph) {
  double n = floor(ph * 0.15915494309189535 + 0.5);
  return (float)(ph - n * 6.283185307179586);
}

__device__ __forceinline__ float sigmf(float x) { return 1.0f / (1.0f + expf(-x)); }

// ---------------- K0: dw weights (all blocks) + block0: fv/before, mixes, gains, stack w, osc params
__global__ __launch_bounds__(256) void k0_prep(
    const float* __restrict__ csig, const float* __restrict__ deform,
    const float* __restrict__ ddmp, const float* __restrict__ dmas,
    const float* __restrict__ dten, const float* __restrict__ ddisp,
    const float* __restrict__ damp, const float* __restrict__ infl,
    const float* __restrict__ smix, const float* __restrict__ router,
    const float* __restrict__ lmix, const float* __restrict__ gains,
    float* __restrict__ wsf, double* __restrict__ wsd, float* __restrict__ out)
{
  int tid = threadIdx.x;
  int t = blockIdx.x * 256 + tid;
  { // deformation softmax + linear interp weight for channel 0
    float src = (t + 0.5f) * (1.0f / 1024.0f) - 0.5f;
    src = fminf(fmaxf(src, 0.0f), 127.0f);
    int lo = (int)src;
    int hi = min(lo + 1, 127);
    float w = src - (float)lo;
    float c0l = 1.0f / (1.0f + expf(deform[128 + lo] - (1.0f + deform[lo])));
    float c0h = 1.0f / (1.0f + expf(deform[128 + hi] - (1.0f + deform[hi])));
    wsf[OFF_DW + t] = c0l * (1.0f - w) + c0h * w;
  }
  if (blockIdx.x == 0) {
    for (int idx = tid; idx < 8192; idx += 256) {   // fv = einsum('becf,cr')
      int e = idx >> 11, r = (idx >> 7) & 15, f = idx & 127;
      float s = 0.f;
      for (int c = 0; c < 16; ++c) s += csig[(e * 16 + c) * 128 + f] * router[c * 16 + r];
      wsf[OFF_FV + idx] = s;
      out[524288 + idx] = s;   // 'before' output
    }
    if (tid < 16) {
      int r = tid;
      float l0 = lmix[r * 2], l1 = lmix[r * 2 + 1];
      float m = fmaxf(l0, l1);
      float e0 = expf(l0 - m), e1 = expf(l1 - m), inv = 1.0f / (e0 + e1);
      wsf[OFF_MIX0 + r] = e0 * inv;
      wsf[OFF_MIX1 + r] = e1 * inv;
      wsf[OFF_GABS + r] = fabsf(gains[r]);
    }
    if (tid < 32) {
      int rx = tid, r = rx >> 1, x = rx & 1;
      float a0 = smix[rx * 3], a1 = smix[rx * 3 + 1], a2 = smix[rx * 3 + 2];
      float mm = fmaxf(a0, fmaxf(a1, a2));
      float e0 = expf(a0 - mm), e1 = expf(a1 - mm), e2 = expf(a2 - mm);
      float inv = 1.0f / (e0 + e1 + e2);
      wsf[OFF_W3 + rx * 3 + 0] = e0 * inv;
      wsf[OFF_W3 + rx * 3 + 1] = e1 * inv;
      wsf[OFF_W3 + rx * 3 + 2] = e2 * inv;
      float* pf = wsf + OFF_PF + rx * 26;
      double* pd = wsd + rx * 8;
      for (int ent = 0; ent < 6; ++ent) {
        int b = ent >> 1, o = ent & 1;
        int id = ((b * 2 + o) * 16 + r) * 2 + x;
        float mass = 2.0f * sigmf(dmas[id]);
        float dampg = 30.0f * sigmf(ddmp[id]);
        float gam = dampg / (2.0f * mass);
        double W = exp((double)dten[id] * 2.302585092994046) / (double)mass;
        float x0v = ddisp[id];
        float ampv = damp[id];
        float infv = 0.f;
        if (b == 1) infv = infl[(o * 16 + r) * 2 + x];
        if (b == 2) infv = infl[((2 + o) * 16 + r) * 2 + x];
        pf[ent] = gam; pf[6 + ent] = ampv; pf[12 + ent] = x0v; pf[18 + ent] = infv;
        pd[ent] = W;
        if (b == 0) {
          double om = sqrt(W - (double)gam * (double)gam);
          pd[6 + o] = om;
          pf[24 + o] = (float)((double)gam * (double)x0v / om);
        }
      }
    }
  }
}

// ---------------- K1: damped-harmonic-oscillator chain -> res_raw + per-block norm partials
__global__ __launch_bounds__(256) void k1_dho(const float* __restrict__ wsf,
    const double* __restrict__ wsd, float* __restrict__ res, float* __restrict__ partials)
{
  int rx = blockIdx.y;
  int t = blockIdx.x * 256 + threadIdx.x;
  const float*  pf = wsf + OFF_PF + rx * 26;
  const double* pd = wsd + rx * 8;
  double tt = (double)t * (10.0 / 131071.0);
  float ttf = (float)tt;

  float o1v = 0.f;
#pragma unroll
  for (int o = 0; o < 2; ++o) {
    float gam = pf[o];
    float sn, cn;
    sincosf(red2pi(pd[6 + o] * tt), &sn, &cn);
    o1v += pf[6 + o] * expf(-gam * ttf) * (pf[12 + o] * cn + pf[24 + o] * sn);
  }
  float prev = o1v, o2v = 0.f, o3v = 0.f;
#pragma unroll
  for (int blk = 1; blk < 3; ++blk) {
    float acc = 0.f;
#pragma unroll
    for (int oo = 0; oo < 2; ++oo) {
      int o = blk * 2 + oo;
      float gam = pf[o];
      float p10 = expf(prev * pf[18 + o] * 2.3025851f);          // 10^(delta)
      float rad = (float)(pd[o] * (double)p10) - gam * gam;
      float om = sqrtf(rad);
      float B = gam * pf[12 + o] / om;
      float sn, cn;
      sincosf(red2pi((double)om * tt), &sn, &cn);
      acc += pf[6 + o] * expf(-gam * ttf) * (pf[12 + o] * cn + B * sn);
    }
    if (blk == 1) o2v = acc; else o3v = acc;
    prev = acc;
  }
  const float* w3 = wsf + OFF_W3 + rx * 3;
  float rv = w3[0] * o1v + w3[1] * o2v + w3[2] * o3v;
  res[(size_t)rx * NS + t] = rv;

  // block-level sumsq -> one private store per block (no same-line atomics)
  __shared__ float bred[4];
  float sq = rv * rv;
#pragma unroll
  for (int off = 32; off; off >>= 1) sq += __shfl_down(sq, off, 64);
  if ((threadIdx.x & 63) == 0) bred[threadIdx.x >> 6] = sq;
  __syncthreads();
  if (threadIdx.x == 0)
    partials[rx * 512 + blockIdx.x] = bred[0] + bred[1] + bred[2] + bred[3];
}

// ---------------- K1r: reduce 512 partials per rx -> norm_acc[rx]
__global__ __launch_bounds__(256) void k1r_reduce(const float* __restrict__ partials,
                                                 float* __restrict__ norm_acc)
{
  int rx = blockIdx.x;
  int tid = threadIdx.x;
  __shared__ float bred[4];
  float s = partials[rx * 512 + tid] + partials[rx * 512 + 256 + tid];
#pragma unroll
  for (int off = 32; off; off >>= 1) s += __shfl_down(s, off, 64);
  if ((tid & 63) == 0) bred[tid >> 6] = s;
  __syncthreads();
  if (tid == 0) norm_acc[rx] = bred[0] + bred[1] + bred[2] + bred[3];
}

// ---------------- K2: gamma-pdf gaussian stacks, dirac-shifted, summed over cpd; per-g sumsq
__global__ __launch_bounds__(256) void k2_gauss(
    const float* __restrict__ means, const float* __restrict__ stds,
    const float* __restrict__ amps, const float* __restrict__ pos,
    float* __restrict__ vg, float* __restrict__ gss)
{
  int g = blockIdx.x;
  int tid = threadIdx.x;
  __shared__ float kS[16], rateS[16], logAS[16], aS[16];
  __shared__ int dS[16];
  __shared__ float red[4];
  if (tid < 16) {
    int c = tid, idx = c * 8 + g;
    double m = fabs((double)means[idx]);
    double s = fabs((double)stds[idx]);
    double k = m / (s + 1e-8); k = k * k;
    double rate = m / (s * s + 1e-8);
    double logA = k * log(rate + 1e-8) - lgamma(k);
    kS[c] = (float)k; rateS[c] = (float)rate; logAS[c] = (float)logA;
    aS[c] = fabsf(amps[idx]);
    int d = 0;
    for (int l = 0; l < 11; ++l) {
      float p0 = pos[(idx * 11 + l) * 2], p1 = pos[(idx * 11 + l) * 2 + 1];
      d = d * 2 + (p1 > p0 ? 1 : 0);
    }
    dS[c] = d;
  }
  __syncthreads();
  const float step = (float)((1.0 - 1e-8) / 2047.0);
  float sumsq = 0.f;
  for (int i = tid; i < 2048; i += 256) {
    float v = 0.f;
    for (int c = 0; c < 16; ++c) {
      int mi = i - dS[c];
      if (mi >= 0) {
        float tm = 1e-8f + (float)mi * step;
        float lp = logAS[c] + (kS[c] - 1.0f) * logf(tm) - rateS[c] * tm;
        v += aS[c] * expf(lp);
      }
    }
    vg[g * 2048 + i] = v;
    sumsq += v * v;
  }
#pragma unroll
  for (int off = 32; off; off >>= 1) sumsq += __shfl_down(sumsq, off, 64);
  if ((tid & 63) == 0) red[tid >> 6] = sumsq;
  __syncthreads();
  if (tid == 0) gss[g] = red[0] + red[1] + red[2] + red[3];
}

// ---------------- K3: impulse = overall_amp[c] * sum_g unitnorm(v_g) * noise
__global__ __launch_bounds__(256) void k3_imp(
    const float* __restrict__ vg, const float* __restrict__ gss,
    const float* __restrict__ ovamp, const float* __restrict__ noise,
    float* __restrict__ imp)
{
  int c = blockIdx.y;
  int i = blockIdx.x * 256 + threadIdx.x;
  float S = 0.f;
#pragma unroll
  for (int g = 0; g < 8; ++g) S += vg[g * 2048 + i] / (sqrtf(gss[g]) + EPSF);
  imp[c * 2048 + i] = ovamp[c] * S * noise[c * 2048 + i];
}

// ---------------- K4: H[rx] = (imp[r] (*) unitnorm2(res[rx])) * mix1[r]  -- 2048-tap dense conv
#define SWZ(i) ((i) ^ (((i) >> 5) & 7))
__global__ __launch_bounds__(256) void k4_H(
    const float* __restrict__ res, const float* __restrict__ imp,
    const float* __restrict__ norm_acc, const float* __restrict__ wsf,
    float* __restrict__ H)
{
  int rx = blockIdx.y, r = rx >> 1;
  int t0 = blockIdx.x * 2048;
  __shared__ float impr[2048];
  __shared__ float win[4096];
  for (int idx = threadIdx.x; idx < 4096; idx += 256) {
    int gsrc = t0 - 2047 + idx;
    float v = (gsrc >= 0 && gsrc < NS) ? res[(size_t)rx * NS + gsrc] : 0.f;
    win[SWZ(idx)] = v;
  }
  for (int idx = threadIdx.x; idx < 2048; idx += 256)
    impr[idx] = imp[r * 2048 + 2047 - idx];
  float n1 = sqrtf(norm_acc[rx]);
  float s1 = 1.0f / (n1 + EPSF);
  float n2 = n1 * s1;
  float scale = s1 * (1.0f / (n2 + EPSF)) * wsf[OFF_MIX1 + r];
  __syncthreads();
  int base = threadIdx.x * 8;
  float acc[8] = {0, 0, 0, 0, 0, 0, 0, 0};
  float w[8];
#pragma unroll
  for (int k = 0; k < 8; ++k) w[k] = win[SWZ(base + k)];
  for (int j0 = 0; j0 < 2048; j0 += 8) {
    float im[8];
#pragma unroll
    for (int u = 0; u < 8; ++u) im[u] = impr[j0 + u];
#pragma unroll
    for (int u = 0; u < 8; ++u) {
      float iv = im[u];
#pragma unroll
      for (int k = 0; k < 8; ++k) acc[k] += iv * w[k];
#pragma unroll
      for (int k = 0; k < 7; ++k) w[k] = w[k + 1];
      w[7] = win[SWZ(base + j0 + u + 8)];
    }
  }
  int i0 = t0 + base;
#pragma unroll
  for (int k = 0; k < 8; ++k) H[(size_t)rx * NS + i0 + k] = acc[k] * scale;
}

// ---------------- K5: cs output = sum_e (spikes (*) imp)
__global__ __launch_bounds__(256) void k5_cs(
    const float* __restrict__ imp, const float* __restrict__ fv, float* __restrict__ out)
{
  int r = blockIdx.y;
  int t = blockIdx.x * 256 + threadIdx.x;
  int q = t >> 10, sl = t & 1023;
  float i1 = imp[r * 2048 + sl];
  float i2 = (q >= 1) ? imp[r * 2048 + 1024 + sl] : 0.f;
  float s = 0.f;
#pragma unroll
  for (int e = 0; e < 4; ++e) {
    float f1 = fv[(e * 16 + r) * 128 + q];
    float f2 = (q >= 1) ? fv[(e * 16 + r) * 128 + q - 1] : 0.f;
    s += f1 * i1 + f2 * i2;
  }
  out[532480 + (size_t)r * NS + t] = s;
}

// ---------------- K6: 128-tap stride conv as Toeplitz GEMM + deform mix + tanh reduction
__global__ __launch_bounds__(256) void k6_final(
    const float* __restrict__ H, const float* __restrict__ imp,
    const float* __restrict__ wsf, float* __restrict__ out)
{
  int r = blockIdx.y;
  int sb = blockIdx.x * 32;
  int rm = r & 3, rq = r >> 2;
  __shared__ float __align__(16) Hs[2][128][32];
  __shared__ float fvp[4][256];
  __shared__ float __align__(16) impsh[64];
  int tid = threadIdx.x;
  for (int idx = tid; idx < 8192; idx += 256) {
    int xx = idx >> 12, p = (idx >> 5) & 127, sl = idx & 31;
    Hs[xx][p][sl] = H[(size_t)(r * 2 + xx) * NS + p * 1024 + sb + sl];
  }
  for (int idx = tid; idx < 1024; idx += 256) {
    int e = idx >> 8, k = idx & 255, f = k - 127;
    fvp[e][k] = (f >= 0 && f < 128) ? wsf[OFF_FV + (e * 16 + r) * 128 + f] : 0.f;
  }
  if (tid < 32) impsh[tid] = imp[r * 2048 + sb + tid];
  else if (tid < 64) impsh[tid] = imp[r * 2048 + 1024 + sb + (tid - 32)];
  __syncthreads();
  int ts = tid & 7, tq = tid >> 3;            // 8 s-groups x 32 q-groups
  const float* dwg = wsf + OFF_DW;
  float d0w[4][4];
#pragma unroll
  for (int i = 0; i < 4; ++i) {
    int q = tq * 4 + i;
    const float4 dv = *(const float4*)&dwg[q * 1024 + sb + ts * 4];
    d0w[i][0] = dv.x; d0w[i][1] = dv.y; d0w[i][2] = dv.z; d0w[i][3] = dv.w;
  }
  float mix0r = wsf[OFF_MIX0 + r];
  const float4 impA = *(const float4*)&impsh[ts * 4];
  const float4 impB = *(const float4*)&impsh[32 + ts * 4];
  float tansum[4][4] = {};
  for (int e = 0; e < 4; ++e) {
    float acc0[4][4] = {}, acc1[4][4] = {};
    for (int p = 0; p < 128; ++p) {
      const float4 b0 = *(const float4*)&Hs[0][p][ts * 4];
      const float4 b1 = *(const float4*)&Hs[1][p][ts * 4];
      float a[4];
#pragma unroll
      for (int i = 0; i < 4; ++i) a[i] = fvp[e][127 + tq * 4 + i - p];
#pragma unroll
      for (int i = 0; i < 4; ++i) {
        acc0[i][0] += a[i] * b0.x; acc0[i][1] += a[i] * b0.y;
        acc0[i][2] += a[i] * b0.z; acc0[i][3] += a[i] * b0.w;
        acc1[i][0] += a[i] * b1.x; acc1[i][1] += a[i] * b1.y;
        acc1[i][2] += a[i] * b1.z; acc1[i][3] += a[i] * b1.w;
      }
    }
    float ge = wsf[OFF_GABS + 4 * e + rq];
#pragma unroll
    for (int i = 0; i < 4; ++i) {
      int q = tq * 4 + i;
      float fq = fvp[e][127 + q], fqm = fvp[e][126 + q];
      float rsv[4] = { fq * impA.x + fqm * impB.x, fq * impA.y + fqm * impB.y,
                       fq * impA.z + fqm * impB.z, fq * impA.w + fqm * impB.w };
#pragma unroll
      for (int j = 0; j < 4; ++j) {
        float d0 = d0w[i][j];
        float conv = d0 * acc0[i][j] + (1.0f - d0) * acc1[i][j];
        float xm = mix0r * rsv[j] + conv;
        tansum[i][j] += tanhf(xm * ge);
      }
    }
  }
#pragma unroll
  for (int i = 0; i < 4; ++i) {
    int q = tq * 4 + i;
#pragma unroll
    for (int j = 0; j < 4; ++j) {
      int t = q * 1024 + sb + ts * 4 + j;
      atomicAdd(&out[(size_t)rm * NS + t], tansum[i][j]);
    }
  }
}

extern "C" void kernel_launch(void* const* d_in, const int* in_sizes, int n_in,
                              void* d_out, int out_size, void* d_ws, size_t ws_size,
                              hipStream_t stream) {
  const float* csig   = (const float*)d_in[0];
  const float* deform = (const float*)d_in[1];
  const float* aem    = (const float*)d_in[2];
  const float* aes    = (const float*)d_in[3];
  const float* aea    = (const float*)d_in[4];
  const float* aep    = (const float*)d_in[5];
  const float* aeo    = (const float*)d_in[6];
  const float* ddmp   = (const float*)d_in[7];
  const float* dmas   = (const float*)d_in[8];
  const float* dten   = (const float*)d_in[9];
  const float* ddisp  = (const float*)d_in[10];
  const float* damp   = (const float*)d_in[11];
  const float* infl   = (const float*)d_in[12];
  const float* smix   = (const float*)d_in[13];
  const float* router = (const float*)d_in[14];
  const float* lmix   = (const float*)d_in[15];
  const float* gains  = (const float*)d_in[16];
  const float* anoise = (const float*)d_in[17];

  float*  wsf = (float*)d_ws;
  double* wsd = (double*)((char*)d_ws + (size_t)WSF_COUNT * 4);
  float*  out = (float*)d_out;

  // zero the atomically-accumulated output region (k6 atomics)
  hipMemsetAsync(d_out, 0, (size_t)524288 * 4, stream);

  k0_prep<<<512, 256, 0, stream>>>(csig, deform, ddmp, dmas, dten, ddisp, damp,
                                   infl, smix, router, lmix, gains, wsf, wsd, out);
  k1_dho<<<dim3(512, 32), 256, 0, stream>>>(wsf, wsd, wsf + OFF_RES, wsf + OFF_PART);
  k1r_reduce<<<32, 256, 0, stream>>>(wsf + OFF_PART, wsf + OFF_NORM);
  k2_gauss<<<8, 256, 0, stream>>>(aem, aes, aea, aep, wsf + OFF_VG, wsf + OFF_GSS);
  k3_imp<<<dim3(8, 16), 256, 0, stream>>>(wsf + OFF_VG, wsf + OFF_GSS, aeo, anoise,
                                          wsf + OFF_IMP);
  k4_H<<<dim3(64, 32), 256, 0, stream>>>(wsf + OFF_RES, wsf + OFF_IMP,
                                         wsf + OFF_NORM, wsf, wsf + OFF_H);
  k5_cs<<<dim3(512, 16), 256, 0, stream>>>(wsf + OFF_IMP, wsf + OFF_FV, out);
  k6_final<<<dim3(32, 16), 256, 0, stream>>>(wsf + OFF_H, wsf + OFF_IMP, wsf, out);
}

// Round 3
// 269.283 us; speedup vs baseline: 4.0920x; 1.9748x over previous
//
#include <hip/hip_runtime.h>
#include <math.h>

#define NS 131072
#define EPSF 1e-8f

// workspace float offsets
#define OFF_RES    0u        // reused: ushort res_bf[32][131072] = ushort idx 0..4194304
                             //         + A-frags (ushort idx 4194304..4727040)
#define OFF_H      4194304u  // 32*131072 H[rx][t] (f32)
#define OFF_IMP    8388608u  // 16*2048
#define OFF_VG     8421376u  // 8*2048
#define OFF_DW     8437760u  // 131072 deformation ch0 weight
#define OFF_FV     8568832u  // 4*16*128 routed frames
#define OFF_NORM   8577024u  // 32 res sumsq
#define OFF_GSS    8577056u  // 8 gauss sumsq
#define OFF_MIX0   8577064u  // 16
#define OFF_MIX1   8577080u  // 16
#define OFF_GABS   8577096u  // 16
#define OFF_W3     8577112u  // 32*3 stack softmax
#define OFF_PF     8577208u  // 32*26 osc params
#define WSF_COUNT  8578040u  // doubles follow: 32*8
#define OFF_PART   8578560u  // 32*512 per-block norm partials

#define AFRAG_USH  4194304u  // ushort offset of A-fragments: [16 r][65 sc][64 lane][8]

typedef __attribute__((ext_vector_type(8))) short short8;
typedef __attribute__((ext_vector_type(4))) float floatx4;
typedef __attribute__((ext_vector_type(4))) unsigned short ushort4v;

__device__ __forceinline__ float red2pi(double ph) {
  double n = floor(ph * 0.15915494309189535 + 0.5);
  return (float)(ph - n * 6.283185307179586);
}

__device__ __forceinline__ float sigmf(float x) { return 1.0f / (1.0f + expf(-x)); }

__device__ __forceinline__ unsigned short f2bf(float x) {
  unsigned u = __float_as_uint(x);
  unsigned r = (u + 0x7FFFu + ((u >> 16) & 1u)) >> 16;
  return (unsigned short)r;
}

// ---------------- K0: dw weights (all blocks) + block0: fv/before, mixes, gains, stack w, osc params
__global__ __launch_bounds__(256) void k0_prep(
    const float* __restrict__ csig, const float* __restrict__ deform,
    const float* __restrict__ ddmp, const float* __restrict__ dmas,
    const float* __restrict__ dten, const float* __restrict__ ddisp,
    const float* __restrict__ damp, const float* __restrict__ infl,
    const float* __restrict__ smix, const float* __restrict__ router,
    const float* __restrict__ lmix, const float* __restrict__ gains,
    float* __restrict__ wsf, double* __restrict__ wsd, float* __restrict__ out)
{
  int tid = threadIdx.x;
  int t = blockIdx.x * 256 + tid;
  { // deformation softmax + linear interp weight for channel 0
    float src = (t + 0.5f) * (1.0f / 1024.0f) - 0.5f;
    src = fminf(fmaxf(src, 0.0f), 127.0f);
    int lo = (int)src;
    int hi = min(lo + 1, 127);
    float w = src - (float)lo;
    float c0l = 1.0f / (1.0f + expf(deform[128 + lo] - (1.0f + deform[lo])));
    float c0h = 1.0f / (1.0f + expf(deform[128 + hi] - (1.0f + deform[hi])));
    wsf[OFF_DW + t] = c0l * (1.0f - w) + c0h * w;
  }
  if (blockIdx.x == 0) {
    for (int idx = tid; idx < 8192; idx += 256) {   // fv = einsum('becf,cr')
      int e = idx >> 11, r = (idx >> 7) & 15, f = idx & 127;
      float s = 0.f;
      for (int c = 0; c < 16; ++c) s += csig[(e * 16 + c) * 128 + f] * router[c * 16 + r];
      wsf[OFF_FV + idx] = s;
      out[524288 + idx] = s;   // 'before' output
    }
    if (tid < 16) {
      int r = tid;
      float l0 = lmix[r * 2], l1 = lmix[r * 2 + 1];
      float m = fmaxf(l0, l1);
      float e0 = expf(l0 - m), e1 = expf(l1 - m), inv = 1.0f / (e0 + e1);
      wsf[OFF_MIX0 + r] = e0 * inv;
      wsf[OFF_MIX1 + r] = e1 * inv;
      wsf[OFF_GABS + r] = fabsf(gains[r]);
    }
    if (tid < 32) {
      int rx = tid, r = rx >> 1, x = rx & 1;
      float a0 = smix[rx * 3], a1 = smix[rx * 3 + 1], a2 = smix[rx * 3 + 2];
      float mm = fmaxf(a0, fmaxf(a1, a2));
      float e0 = expf(a0 - mm), e1 = expf(a1 - mm), e2 = expf(a2 - mm);
      float inv = 1.0f / (e0 + e1 + e2);
      wsf[OFF_W3 + rx * 3 + 0] = e0 * inv;
      wsf[OFF_W3 + rx * 3 + 1] = e1 * inv;
      wsf[OFF_W3 + rx * 3 + 2] = e2 * inv;
      float* pf = wsf + OFF_PF + rx * 26;
      double* pd = wsd + rx * 8;
      for (int ent = 0; ent < 6; ++ent) {
        int b = ent >> 1, o = ent & 1;
        int id = ((b * 2 + o) * 16 + r) * 2 + x;
        float mass = 2.0f * sigmf(dmas[id]);
        float dampg = 30.0f * sigmf(ddmp[id]);
        float gam = dampg / (2.0f * mass);
        double W = exp((double)dten[id] * 2.302585092994046) / (double)mass;
        float x0v = ddisp[id];
        float ampv = damp[id];
        float infv = 0.f;
        if (b == 1) infv = infl[(o * 16 + r) * 2 + x];
        if (b == 2) infv = infl[((2 + o) * 16 + r) * 2 + x];
        pf[ent] = gam; pf[6 + ent] = ampv; pf[12 + ent] = x0v; pf[18 + ent] = infv;
        pd[ent] = W;
        if (b == 0) {
          double om = sqrt(W - (double)gam * (double)gam);
          pd[6 + o] = om;
          pf[24 + o] = (float)((double)gam * (double)x0v / om);
        }
      }
    }
  }
}

// ---------------- K1: DHO chain -> res (bf16) + per-block norm partials (f32)
__global__ __launch_bounds__(256) void k1_dho(const float* __restrict__ wsf,
    const double* __restrict__ wsd, unsigned short* __restrict__ resb,
    float* __restrict__ partials)
{
  int rx = blockIdx.y;
  int t = blockIdx.x * 256 + threadIdx.x;
  const float*  pf = wsf + OFF_PF + rx * 26;
  const double* pd = wsd + rx * 8;
  double tt = (double)t * (10.0 / 131071.0);
  float ttf = (float)tt;

  float o1v = 0.f;
#pragma unroll
  for (int o = 0; o < 2; ++o) {
    float gam = pf[o];
    float sn, cn;
    sincosf(red2pi(pd[6 + o] * tt), &sn, &cn);
    o1v += pf[6 + o] * expf(-gam * ttf) * (pf[12 + o] * cn + pf[24 + o] * sn);
  }
  float prev = o1v, o2v = 0.f, o3v = 0.f;
#pragma unroll
  for (int blk = 1; blk < 3; ++blk) {
    float acc = 0.f;
#pragma unroll
    for (int oo = 0; oo < 2; ++oo) {
      int o = blk * 2 + oo;
      float gam = pf[o];
      float p10 = expf(prev * pf[18 + o] * 2.3025851f);
      float rad = (float)(pd[o] * (double)p10) - gam * gam;
      float om = sqrtf(rad);
      float B = gam * pf[12 + o] / om;
      float sn, cn;
      sincosf(red2pi((double)om * tt), &sn, &cn);
      acc += pf[6 + o] * expf(-gam * ttf) * (pf[12 + o] * cn + B * sn);
    }
    if (blk == 1) o2v = acc; else o3v = acc;
    prev = acc;
  }
  const float* w3 = wsf + OFF_W3 + rx * 3;
  float rv = w3[0] * o1v + w3[1] * o2v + w3[2] * o3v;
  resb[(size_t)rx * NS + t] = f2bf(rv);

  __shared__ float bred[4];
  float sq = rv * rv;
#pragma unroll
  for (int off = 32; off; off >>= 1) sq += __shfl_down(sq, off, 64);
  if ((threadIdx.x & 63) == 0) bred[threadIdx.x >> 6] = sq;
  __syncthreads();
  if (threadIdx.x == 0)
    partials[rx * 512 + blockIdx.x] = bred[0] + bred[1] + bred[2] + bred[3];
}

// ---------------- K1r: reduce 512 partials per rx -> norm_acc[rx]
__global__ __launch_bounds__(256) void k1r_reduce(const float* __restrict__ partials,
                                                 float* __restrict__ norm_acc)
{
  int rx = blockIdx.x;
  int tid = threadIdx.x;
  __shared__ float bred[4];
  float s = partials[rx * 512 + tid] + partials[rx * 512 + 256 + tid];
#pragma unroll
  for (int off = 32; off; off >>= 1) s += __shfl_down(s, off, 64);
  if ((tid & 63) == 0) bred[tid >> 6] = s;
  __syncthreads();
  if (tid == 0) norm_acc[rx] = bred[0] + bred[1] + bred[2] + bred[3];
}

// ---------------- K2: gamma-pdf gaussian stacks
__global__ __launch_bounds__(256) void k2_gauss(
    const float* __restrict__ means, const float* __restrict__ stds,
    const float* __restrict__ amps, const float* __restrict__ pos,
    float* __restrict__ vg, float* __restrict__ gss)
{
  int g = blockIdx.x;
  int tid = threadIdx.x;
  __shared__ float kS[16], rateS[16], logAS[16], aS[16];
  __shared__ int dS[16];
  __shared__ float red[4];
  if (tid < 16) {
    int c = tid, idx = c * 8 + g;
    double m = fabs((double)means[idx]);
    double s = fabs((double)stds[idx]);
    double k = m / (s + 1e-8); k = k * k;
    double rate = m / (s * s + 1e-8);
    double logA = k * log(rate + 1e-8) - lgamma(k);
    kS[c] = (float)k; rateS[c] = (float)rate; logAS[c] = (float)logA;
    aS[c] = fabsf(amps[idx]);
    int d = 0;
    for (int l = 0; l < 11; ++l) {
      float p0 = pos[(idx * 11 + l) * 2], p1 = pos[(idx * 11 + l) * 2 + 1];
      d = d * 2 + (p1 > p0 ? 1 : 0);
    }
    dS[c] = d;
  }
  __syncthreads();
  const float step = (float)((1.0 - 1e-8) / 2047.0);
  float sumsq = 0.f;
  for (int i = tid; i < 2048; i += 256) {
    float v = 0.f;
    for (int c = 0; c < 16; ++c) {
      int mi = i - dS[c];
      if (mi >= 0) {
        float tm = 1e-8f + (float)mi * step;
        float lp = logAS[c] + (kS[c] - 1.0f) * logf(tm) - rateS[c] * tm;
        v += aS[c] * expf(lp);
      }
    }
    vg[g * 2048 + i] = v;
    sumsq += v * v;
  }
#pragma unroll
  for (int off = 32; off; off >>= 1) sumsq += __shfl_down(sumsq, off, 64);
  if ((tid & 63) == 0) red[tid >> 6] = sumsq;
  __syncthreads();
  if (tid == 0) gss[g] = red[0] + red[1] + red[2] + red[3];
}

// ---------------- K3: impulse = overall_amp[c] * sum_g unitnorm(v_g) * noise
__global__ __launch_bounds__(256) void k3_imp(
    const float* __restrict__ vg, const float* __restrict__ gss,
    const float* __restrict__ ovamp, const float* __restrict__ noise,
    float* __restrict__ imp)
{
  int c = blockIdx.y;
  int i = blockIdx.x * 256 + threadIdx.x;
  float S = 0.f;
#pragma unroll
  for (int g = 0; g < 8; ++g) S += vg[g * 2048 + i] / (sqrtf(gss[g]) + EPSF);
  imp[c * 2048 + i] = ovamp[c] * S * noise[c * 2048 + i];
}

// ---------------- KA: build MFMA A-fragments of the block-Toeplitz imp matrix
// A_sc[m][k] = imp[32*sc + m - k + 32*(k>=16)], lane-ready:
// lane: m=lane&15, quad=lane>>4; value(j) = imp[32*sc + m - 8*q' - j], q'={0,1,-2,-1}
__global__ __launch_bounds__(256) void kA_frag(
    const float* __restrict__ imp, unsigned short* __restrict__ abf)
{
  int gid = blockIdx.x * 256 + threadIdx.x;   // 16*65*64 = 66560
  if (gid >= 66560) return;
  int r = gid / (65 * 64);
  int rem = gid % (65 * 64);
  int sc = rem >> 6, lane = rem & 63;
  int m = lane & 15, quad = lane >> 4;
  int qp = (quad < 2) ? quad : quad - 4;
  int base = 32 * sc + m - 8 * qp;
  short8 v;
#pragma unroll
  for (int j = 0; j < 8; ++j) {
    int idx = base - j;
    unsigned short b = 0;
    if (idx >= 0 && idx < 2048) b = f2bf(imp[r * 2048 + idx]);
    v[j] = (short)b;
  }
  *(short8*)&abf[(size_t)gid * 8] = v;
}

// ---------------- K4: H via MFMA block-Toeplitz: H[:,n] = sum_s G_s X[:,n-s]
__global__ __launch_bounds__(256) void k4_mfma(
    const unsigned short* __restrict__ resb, const unsigned short* __restrict__ abf,
    const float* __restrict__ norm_acc, const float* __restrict__ wsf,
    float* __restrict__ H)
{
  int rx = blockIdx.y, r = rx >> 1;
  int n0 = blockIdx.x * 256;                       // 256 columns of 16 samples
  __shared__ __align__(16) unsigned short Xs[9280]; // 386 cols x stride 24
  int tid = threadIdx.x;
  for (int i = tid; i < 1544; i += 256) {          // 386*16/4 ushort4 chunks
    int q_rel = i >> 2, p4 = (i & 3) * 4;
    int q = n0 - 130 + q_rel;
    ushort4v v = {0, 0, 0, 0};
    if (q >= 0) v = *(const ushort4v*)&resb[(size_t)rx * NS + q * 16 + p4];
    *(ushort4v*)&Xs[q_rel * 24 + p4] = v;
  }
  __syncthreads();
  int lane = tid & 63, w = tid >> 6;
  int quad = lane >> 4, nl = lane & 15;
  float n1 = sqrtf(norm_acc[rx]);
  float s1 = 1.0f / (n1 + EPSF);
  float scale = s1 * (1.0f / (n1 * s1 + EPSF)) * wsf[OFF_MIX1 + r];
  const short8* af = (const short8*)(abf) + (size_t)r * 65 * 64;
  floatx4 acc0 = {0,0,0,0}, acc1 = {0,0,0,0}, acc2 = {0,0,0,0}, acc3 = {0,0,0,0};
  const char* xb0 = (const char*)Xs + (size_t)(130 + w * 64 + nl - (quad >> 1)) * 48
                    + (quad & 1) * 16;
#pragma unroll 4
  for (int sc = 0; sc < 65; ++sc) {
    short8 a = af[sc * 64 + lane];
    const char* xb = xb0 - 96 * sc;
    acc0 = __builtin_amdgcn_mfma_f32_16x16x32_bf16(a, *(const short8*)(xb       ), acc0, 0, 0, 0);
    acc1 = __builtin_amdgcn_mfma_f32_16x16x32_bf16(a, *(const short8*)(xb +  768), acc1, 0, 0, 0);
    acc2 = __builtin_amdgcn_mfma_f32_16x16x32_bf16(a, *(const short8*)(xb + 1536), acc2, 0, 0, 0);
    acc3 = __builtin_amdgcn_mfma_f32_16x16x32_bf16(a, *(const short8*)(xb + 2304), acc3, 0, 0, 0);
  }
  // D[m][n]: n = lane&15, m = quad*4 + i ; t = 16*(n0 + w*64 + g*16 + n) + m
  float* hp = H + (size_t)rx * NS + 16 * (n0 + w * 64 + nl) + quad * 4;
#pragma unroll
  for (int i = 0; i < 4; ++i) {
    hp[i]       = acc0[i] * scale;
    hp[256 + i] = acc1[i] * scale;
    hp[512 + i] = acc2[i] * scale;
    hp[768 + i] = acc3[i] * scale;
  }
}

// ---------------- K5: cs output = sum_e (spikes (*) imp)
__global__ __launch_bounds__(256) void k5_cs(
    const float* __restrict__ imp, const float* __restrict__ fv, float* __restrict__ out)
{
  int r = blockIdx.y;
  int t = blockIdx.x * 256 + threadIdx.x;
  int q = t >> 10, sl = t & 1023;
  float i1 = imp[r * 2048 + sl];
  float i2 = (q >= 1) ? imp[r * 2048 + 1024 + sl] : 0.f;
  float s = 0.f;
#pragma unroll
  for (int e = 0; e < 4; ++e) {
    float f1 = fv[(e * 16 + r) * 128 + q];
    float f2 = (q >= 1) ? fv[(e * 16 + r) * 128 + q - 1] : 0.f;
    s += f1 * i1 + f2 * i2;
  }
  out[532480 + (size_t)r * NS + t] = s;
}

// ---------------- K6: 128-tap stride conv as Toeplitz GEMM + deform mix + tanh reduction
__global__ __launch_bounds__(256) void k6_final(
    const float* __restrict__ H, const float* __restrict__ imp,
    const float* __restrict__ wsf, float* __restrict__ out)
{
  int r = blockIdx.y;
  int sb = blockIdx.x * 32;
  int rm = r & 3, rq = r >> 2;
  __shared__ float __align__(16) Hs[2][128][32];
  __shared__ float fvp[4][256];
  __shared__ float __align__(16) impsh[64];
  int tid = threadIdx.x;
  for (int idx = tid; idx < 8192; idx += 256) {
    int xx = idx >> 12, p = (idx >> 5) & 127, sl = idx & 31;
    Hs[xx][p][sl] = H[(size_t)(r * 2 + xx) * NS + p * 1024 + sb + sl];
  }
  for (int idx = tid; idx < 1024; idx += 256) {
    int e = idx >> 8, k = idx & 255, f = k - 127;
    fvp[e][k] = (f >= 0 && f < 128) ? wsf[OFF_FV + (e * 16 + r) * 128 + f] : 0.f;
  }
  if (tid < 32) impsh[tid] = imp[r * 2048 + sb + tid];
  else if (tid < 64) impsh[tid] = imp[r * 2048 + 1024 + sb + (tid - 32)];
  __syncthreads();
  int ts = tid & 7, tq = tid >> 3;
  const float* dwg = wsf + OFF_DW;
  float d0w[4][4];
#pragma unroll
  for (int i = 0; i < 4; ++i) {
    int q = tq * 4 + i;
    const float4 dv = *(const float4*)&dwg[q * 1024 + sb + ts * 4];
    d0w[i][0] = dv.x; d0w[i][1] = dv.y; d0w[i][2] = dv.z; d0w[i][3] = dv.w;
  }
  float mix0r = wsf[OFF_MIX0 + r];
  const float4 impA = *(const float4*)&impsh[ts * 4];
  const float4 impB = *(const float4*)&impsh[32 + ts * 4];
  float tansum[4][4] = {};
  for (int e = 0; e < 4; ++e) {
    float acc0[4][4] = {}, acc1[4][4] = {};
    for (int p = 0; p < 128; ++p) {
      const float4 b0 = *(const float4*)&Hs[0][p][ts * 4];
      const float4 b1 = *(const float4*)&Hs[1][p][ts * 4];
      float a[4];
#pragma unroll
      for (int i = 0; i < 4; ++i) a[i] = fvp[e][127 + tq * 4 + i - p];
#pragma unroll
      for (int i = 0; i < 4; ++i) {
        acc0[i][0] += a[i] * b0.x; acc0[i][1] += a[i] * b0.y;
        acc0[i][2] += a[i] * b0.z; acc0[i][3] += a[i] * b0.w;
        acc1[i][0] += a[i] * b1.x; acc1[i][1] += a[i] * b1.y;
        acc1[i][2] += a[i] * b1.z; acc1[i][3] += a[i] * b1.w;
      }
    }
    float ge = wsf[OFF_GABS + 4 * e + rq];
#pragma unroll
    for (int i = 0; i < 4; ++i) {
      int q = tq * 4 + i;
      float fq = fvp[e][127 + q], fqm = fvp[e][126 + q];
      float rsv[4] = { fq * impA.x + fqm * impB.x, fq * impA.y + fqm * impB.y,
                       fq * impA.z + fqm * impB.z, fq * impA.w + fqm * impB.w };
#pragma unroll
      for (int j = 0; j < 4; ++j) {
        float d0 = d0w[i][j];
        float conv = d0 * acc0[i][j] + (1.0f - d0) * acc1[i][j];
        float xm = mix0r * rsv[j] + conv;
        tansum[i][j] += tanhf(xm * ge);
      }
    }
  }
#pragma unroll
  for (int i = 0; i < 4; ++i) {
    int q = tq * 4 + i;
#pragma unroll
    for (int j = 0; j < 4; ++j) {
      int t = q * 1024 + sb + ts * 4 + j;
      atomicAdd(&out[(size_t)rm * NS + t], tansum[i][j]);
    }
  }
}

extern "C" void kernel_launch(void* const* d_in, const int* in_sizes, int n_in,
                              void* d_out, int out_size, void* d_ws, size_t ws_size,
                              hipStream_t stream) {
  const float* csig   = (const float*)d_in[0];
  const float* deform = (const float*)d_in[1];
  const float* aem    = (const float*)d_in[2];
  const float* aes    = (const float*)d_in[3];
  const float* aea    = (const float*)d_in[4];
  const float* aep    = (const float*)d_in[5];
  const float* aeo    = (const float*)d_in[6];
  const float* ddmp   = (const float*)d_in[7];
  const float* dmas   = (const float*)d_in[8];
  const float* dten   = (const float*)d_in[9];
  const float* ddisp  = (const float*)d_in[10];
  const float* damp   = (const float*)d_in[11];
  const float* infl   = (const float*)d_in[12];
  const float* smix   = (const float*)d_in[13];
  const float* router = (const float*)d_in[14];
  const float* lmix   = (const float*)d_in[15];
  const float* gains  = (const float*)d_in[16];
  const float* anoise = (const float*)d_in[17];

  float*  wsf = (float*)d_ws;
  double* wsd = (double*)((char*)d_ws + (size_t)WSF_COUNT * 4);
  unsigned short* resb = (unsigned short*)d_ws;
  unsigned short* abf  = (unsigned short*)d_ws + AFRAG_USH;
  float*  out = (float*)d_out;

  hipMemsetAsync(d_out, 0, (size_t)524288 * 4, stream);

  k0_prep<<<512, 256, 0, stream>>>(csig, deform, ddmp, dmas, dten, ddisp, damp,
                                   infl, smix, router, lmix, gains, wsf, wsd, out);
  k1_dho<<<dim3(512, 32), 256, 0, stream>>>(wsf, wsd, resb, wsf + OFF_PART);
  k1r_reduce<<<32, 256, 0, stream>>>(wsf + OFF_PART, wsf + OFF_NORM);
  k2_gauss<<<8, 256, 0, stream>>>(aem, aes, aea, aep, wsf + OFF_VG, wsf + OFF_GSS);
  k3_imp<<<dim3(8, 16), 256, 0, stream>>>(wsf + OFF_VG, wsf + OFF_GSS, aeo, anoise,
                                          wsf + OFF_IMP);
  kA_frag<<<260, 256, 0, stream>>>(wsf + OFF_IMP, abf);
  k4_mfma<<<dim3(32, 32), 256, 0, stream>>>(resb, abf, wsf + OFF_NORM, wsf,
                                            wsf + OFF_H);
  k5_cs<<<dim3(512, 16), 256, 0, stream>>>(wsf + OFF_IMP, wsf + OFF_FV, out);
  k6_final<<<dim3(32, 16), 256, 0, stream>>>(wsf + OFF_H, wsf + OFF_IMP, wsf, out);
}

// Round 4
// 232.718 us; speedup vs baseline: 4.7349x; 1.1571x over previous
//
#include <hip/hip_runtime.h>
#include <math.h>

#define NS 131072
#define EPSF 1e-8f

// workspace float offsets
#define OFF_RES    0u        // ushort res_bf[32][131072] = ushort idx 0..4194304
#define OFF_H      4194304u  // 32*131072 H[rx][t] (f32)
#define OFF_IMP    8388608u  // 16*2048
#define OFF_VG     8421376u  // 8*2048
#define OFF_DW     8437760u  // 131072 deformation ch0 weight
#define OFF_FV     8568832u  // 4*16*128 routed frames
#define OFF_NORM   8577024u  // 32 res sumsq
#define OFF_GSS    8577056u  // 8 gauss sumsq
#define OFF_MIX0   8577064u  // 16
#define OFF_MIX1   8577080u  // 16
#define OFF_GABS   8577096u  // 16
#define OFF_W3     8577112u  // 32*3 stack softmax
#define OFF_PF     8577208u  // 32*26 osc params
#define WSF_COUNT  8578040u  // doubles follow: 32*8
#define OFF_PART   8578560u  // 32*512 per-block norm partials

#define AFRAG_USH  4194304u  // ushort offset: imp A-frags [16 r][65 sc][64 lane][8]
#define ABF2_USH   4726784u  // ushort offset: fv-Toeplitz A-frags [16r][4e][8mt][4kt][64][8]

typedef __attribute__((ext_vector_type(8))) short short8;
typedef __attribute__((ext_vector_type(4))) float floatx4;
typedef __attribute__((ext_vector_type(4))) unsigned short ushort4v;

__device__ __forceinline__ float red2pi(double ph) {
  double n = floor(ph * 0.15915494309189535 + 0.5);
  return (float)(ph - n * 6.283185307179586);
}

__device__ __forceinline__ float sigmf(float x) { return 1.0f / (1.0f + expf(-x)); }

__device__ __forceinline__ unsigned short f2bf(float x) {
  unsigned u = __float_as_uint(x);
  unsigned r = (u + 0x7FFFu + ((u >> 16) & 1u)) >> 16;
  return (unsigned short)r;
}

// ---------------- K0: dw weights (all blocks) + block0: fv/before, mixes, gains, stack w, osc params
__global__ __launch_bounds__(256) void k0_prep(
    const float* __restrict__ csig, const float* __restrict__ deform,
    const float* __restrict__ ddmp, const float* __restrict__ dmas,
    const float* __restrict__ dten, const float* __restrict__ ddisp,
    const float* __restrict__ damp, const float* __restrict__ infl,
    const float* __restrict__ smix, const float* __restrict__ router,
    const float* __restrict__ lmix, const float* __restrict__ gains,
    float* __restrict__ wsf, double* __restrict__ wsd, float* __restrict__ out)
{
  int tid = threadIdx.x;
  int t = blockIdx.x * 256 + tid;
  { // deformation softmax + linear interp weight for channel 0
    float src = (t + 0.5f) * (1.0f / 1024.0f) - 0.5f;
    src = fminf(fmaxf(src, 0.0f), 127.0f);
    int lo = (int)src;
    int hi = min(lo + 1, 127);
    float w = src - (float)lo;
    float c0l = 1.0f / (1.0f + expf(deform[128 + lo] - (1.0f + deform[lo])));
    float c0h = 1.0f / (1.0f + expf(deform[128 + hi] - (1.0f + deform[hi])));
    wsf[OFF_DW + t] = c0l * (1.0f - w) + c0h * w;
  }
  if (blockIdx.x == 0) {
    for (int idx = tid; idx < 8192; idx += 256) {   // fv = einsum('becf,cr')
      int e = idx >> 11, r = (idx >> 7) & 15, f = idx & 127;
      float s = 0.f;
      for (int c = 0; c < 16; ++c) s += csig[(e * 16 + c) * 128 + f] * router[c * 16 + r];
      wsf[OFF_FV + idx] = s;
      out[524288 + idx] = s;   // 'before' output
    }
    if (tid < 16) {
      int r = tid;
      float l0 = lmix[r * 2], l1 = lmix[r * 2 + 1];
      float m = fmaxf(l0, l1);
      float e0 = expf(l0 - m), e1 = expf(l1 - m), inv = 1.0f / (e0 + e1);
      wsf[OFF_MIX0 + r] = e0 * inv;
      wsf[OFF_MIX1 + r] = e1 * inv;
      wsf[OFF_GABS + r] = fabsf(gains[r]);
    }
    if (tid < 32) {
      int rx = tid, r = rx >> 1, x = rx & 1;
      float a0 = smix[rx * 3], a1 = smix[rx * 3 + 1], a2 = smix[rx * 3 + 2];
      float mm = fmaxf(a0, fmaxf(a1, a2));
      float e0 = expf(a0 - mm), e1 = expf(a1 - mm), e2 = expf(a2 - mm);
      float inv = 1.0f / (e0 + e1 + e2);
      wsf[OFF_W3 + rx * 3 + 0] = e0 * inv;
      wsf[OFF_W3 + rx * 3 + 1] = e1 * inv;
      wsf[OFF_W3 + rx * 3 + 2] = e2 * inv;
      float* pf = wsf + OFF_PF + rx * 26;
      double* pd = wsd + rx * 8;
      for (int ent = 0; ent < 6; ++ent) {
        int b = ent >> 1, o = ent & 1;
        int id = ((b * 2 + o) * 16 + r) * 2 + x;
        float mass = 2.0f * sigmf(dmas[id]);
        float dampg = 30.0f * sigmf(ddmp[id]);
        float gam = dampg / (2.0f * mass);
        double W = exp((double)dten[id] * 2.302585092994046) / (double)mass;
        float x0v = ddisp[id];
        float ampv = damp[id];
        float infv = 0.f;
        if (b == 1) infv = infl[(o * 16 + r) * 2 + x];
        if (b == 2) infv = infl[((2 + o) * 16 + r) * 2 + x];
        pf[ent] = gam; pf[6 + ent] = ampv; pf[12 + ent] = x0v; pf[18 + ent] = infv;
        pd[ent] = W;
        if (b == 0) {
          double om = sqrt(W - (double)gam * (double)gam);
          pd[6 + o] = om;
          pf[24 + o] = (float)((double)gam * (double)x0v / om);
        }
      }
    }
  }
}

// ---------------- K1: DHO chain -> res (bf16) + per-block norm partials (f32)
__global__ __launch_bounds__(256) void k1_dho(const float* __restrict__ wsf,
    const double* __restrict__ wsd, unsigned short* __restrict__ resb,
    float* __restrict__ partials)
{
  int rx = blockIdx.y;
  int t = blockIdx.x * 256 + threadIdx.x;
  const float*  pf = wsf + OFF_PF + rx * 26;
  const double* pd = wsd + rx * 8;
  double tt = (double)t * (10.0 / 131071.0);
  float ttf = (float)tt;

  float o1v = 0.f;
#pragma unroll
  for (int o = 0; o < 2; ++o) {
    float gam = pf[o];
    float sn, cn;
    sincosf(red2pi(pd[6 + o] * tt), &sn, &cn);
    o1v += pf[6 + o] * expf(-gam * ttf) * (pf[12 + o] * cn + pf[24 + o] * sn);
  }
  float prev = o1v, o2v = 0.f, o3v = 0.f;
#pragma unroll
  for (int blk = 1; blk < 3; ++blk) {
    float acc = 0.f;
#pragma unroll
    for (int oo = 0; oo < 2; ++oo) {
      int o = blk * 2 + oo;
      float gam = pf[o];
      float p10 = expf(prev * pf[18 + o] * 2.3025851f);
      float rad = (float)(pd[o] * (double)p10) - gam * gam;
      float om = sqrtf(rad);
      float B = gam * pf[12 + o] / om;
      float sn, cn;
      sincosf(red2pi((double)om * tt), &sn, &cn);
      acc += pf[6 + o] * expf(-gam * ttf) * (pf[12 + o] * cn + B * sn);
    }
    if (blk == 1) o2v = acc; else o3v = acc;
    prev = acc;
  }
  const float* w3 = wsf + OFF_W3 + rx * 3;
  float rv = w3[0] * o1v + w3[1] * o2v + w3[2] * o3v;
  resb[(size_t)rx * NS + t] = f2bf(rv);

  __shared__ float bred[4];
  float sq = rv * rv;
#pragma unroll
  for (int off = 32; off; off >>= 1) sq += __shfl_down(sq, off, 64);
  if ((threadIdx.x & 63) == 0) bred[threadIdx.x >> 6] = sq;
  __syncthreads();
  if (threadIdx.x == 0)
    partials[rx * 512 + blockIdx.x] = bred[0] + bred[1] + bred[2] + bred[3];
}

// ---------------- K1r: reduce 512 partials per rx -> norm_acc[rx]
__global__ __launch_bounds__(256) void k1r_reduce(const float* __restrict__ partials,
                                                 float* __restrict__ norm_acc)
{
  int rx = blockIdx.x;
  int tid = threadIdx.x;
  __shared__ float bred[4];
  float s = partials[rx * 512 + tid] + partials[rx * 512 + 256 + tid];
#pragma unroll
  for (int off = 32; off; off >>= 1) s += __shfl_down(s, off, 64);
  if ((tid & 63) == 0) bred[tid >> 6] = s;
  __syncthreads();
  if (tid == 0) norm_acc[rx] = bred[0] + bred[1] + bred[2] + bred[3];
}

// ---------------- K2: gamma-pdf gaussian stacks
__global__ __launch_bounds__(256) void k2_gauss(
    const float* __restrict__ means, const float* __restrict__ stds,
    const float* __restrict__ amps, const float* __restrict__ pos,
    float* __restrict__ vg, float* __restrict__ gss)
{
  int g = blockIdx.x;
  int tid = threadIdx.x;
  __shared__ float kS[16], rateS[16], logAS[16], aS[16];
  __shared__ int dS[16];
  __shared__ float red[4];
  if (tid < 16) {
    int c = tid, idx = c * 8 + g;
    double m = fabs((double)means[idx]);
    double s = fabs((double)stds[idx]);
    double k = m / (s + 1e-8); k = k * k;
    double rate = m / (s * s + 1e-8);
    double logA = k * log(rate + 1e-8) - lgamma(k);
    kS[c] = (float)k; rateS[c] = (float)rate; logAS[c] = (float)logA;
    aS[c] = fabsf(amps[idx]);
    int d = 0;
    for (int l = 0; l < 11; ++l) {
      float p0 = pos[(idx * 11 + l) * 2], p1 = pos[(idx * 11 + l) * 2 + 1];
      d = d * 2 + (p1 > p0 ? 1 : 0);
    }
    dS[c] = d;
  }
  __syncthreads();
  const float step = (float)((1.0 - 1e-8) / 2047.0);
  float sumsq = 0.f;
  for (int i = tid; i < 2048; i += 256) {
    float v = 0.f;
    for (int c = 0; c < 16; ++c) {
      int mi = i - dS[c];
      if (mi >= 0) {
        float tm = 1e-8f + (float)mi * step;
        float lp = logAS[c] + (kS[c] - 1.0f) * logf(tm) - rateS[c] * tm;
        v += aS[c] * expf(lp);
      }
    }
    vg[g * 2048 + i] = v;
    sumsq += v * v;
  }
#pragma unroll
  for (int off = 32; off; off >>= 1) sumsq += __shfl_down(sumsq, off, 64);
  if ((tid & 63) == 0) red[tid >> 6] = sumsq;
  __syncthreads();
  if (tid == 0) gss[g] = red[0] + red[1] + red[2] + red[3];
}

// ---------------- K3: impulse = overall_amp[c] * sum_g unitnorm(v_g) * noise
__global__ __launch_bounds__(256) void k3_imp(
    const float* __restrict__ vg, const float* __restrict__ gss,
    const float* __restrict__ ovamp, const float* __restrict__ noise,
    float* __restrict__ imp)
{
  int c = blockIdx.y;
  int i = blockIdx.x * 256 + threadIdx.x;
  float S = 0.f;
#pragma unroll
  for (int g = 0; g < 8; ++g) S += vg[g * 2048 + i] / (sqrtf(gss[g]) + EPSF);
  imp[c * 2048 + i] = ovamp[c] * S * noise[c * 2048 + i];
}

// ---------------- KA: build MFMA A-fragments of the block-Toeplitz imp matrix (for k4)
__global__ __launch_bounds__(256) void kA_frag(
    const float* __restrict__ imp, unsigned short* __restrict__ abf)
{
  int gid = blockIdx.x * 256 + threadIdx.x;   // 16*65*64 = 66560
  if (gid >= 66560) return;
  int r = gid / (65 * 64);
  int rem = gid % (65 * 64);
  int sc = rem >> 6, lane = rem & 63;
  int m = lane & 15, quad = lane >> 4;
  int qp = (quad < 2) ? quad : quad - 4;
  int base = 32 * sc + m - 8 * qp;
  short8 v;
#pragma unroll
  for (int j = 0; j < 8; ++j) {
    int idx = base - j;
    unsigned short b = 0;
    if (idx >= 0 && idx < 2048) b = f2bf(imp[r * 2048 + idx]);
    v[j] = (short)b;
  }
  *(short8*)&abf[(size_t)gid * 8] = v;
}

// ---------------- KA2: build MFMA A-fragments of the fv-Toeplitz matrix (for k6)
// A[m][k] = fv_e[mt*16+m - kt*32 - k], lane: m=lane&15, k=quad*8+j
__global__ __launch_bounds__(256) void kA2_frag(
    const float* __restrict__ wsf, unsigned short* __restrict__ abf2)
{
  int gid = blockIdx.x * 256 + threadIdx.x;   // 131072
  int lane = gid & 63;
  int kt = (gid >> 6) & 3;
  int mt = (gid >> 8) & 7;
  int e  = (gid >> 11) & 3;
  int r  = (gid >> 13) & 15;
  int m = lane & 15, quad = lane >> 4;
  int base = mt * 16 + m - kt * 32 - quad * 8;
  const float* fve = wsf + OFF_FV + (e * 16 + r) * 128;
  short8 v;
#pragma unroll
  for (int j = 0; j < 8; ++j) {
    int f = base - j;
    unsigned short b = 0;
    if (f >= 0 && f < 128) b = f2bf(fve[f]);
    v[j] = (short)b;
  }
  *(short8*)&abf2[(size_t)gid * 8] = v;
}

// ---------------- K4: H via MFMA block-Toeplitz: H[:,n] = sum_s G_s X[:,n-s]
__global__ __launch_bounds__(256) void k4_mfma(
    const unsigned short* __restrict__ resb, const unsigned short* __restrict__ abf,
    const float* __restrict__ norm_acc, const float* __restrict__ wsf,
    float* __restrict__ H)
{
  int rx = blockIdx.y, r = rx >> 1;
  int n0 = blockIdx.x * 256;                       // 256 columns of 16 samples
  __shared__ __align__(16) unsigned short Xs[9280]; // 386 cols x stride 24
  int tid = threadIdx.x;
  for (int i = tid; i < 1544; i += 256) {          // 386*16/4 ushort4 chunks
    int q_rel = i >> 2, p4 = (i & 3) * 4;
    int q = n0 - 130 + q_rel;
    ushort4v v = {0, 0, 0, 0};
    if (q >= 0) v = *(const ushort4v*)&resb[(size_t)rx * NS + q * 16 + p4];
    *(ushort4v*)&Xs[q_rel * 24 + p4] = v;
  }
  __syncthreads();
  int lane = tid & 63, w = tid >> 6;
  int quad = lane >> 4, nl = lane & 15;
  float n1 = sqrtf(norm_acc[rx]);
  float s1 = 1.0f / (n1 + EPSF);
  float scale = s1 * (1.0f / (n1 * s1 + EPSF)) * wsf[OFF_MIX1 + r];
  const short8* af = (const short8*)(abf) + (size_t)r * 65 * 64;
  floatx4 acc0 = {0,0,0,0}, acc1 = {0,0,0,0}, acc2 = {0,0,0,0}, acc3 = {0,0,0,0};
  const char* xb0 = (const char*)Xs + (size_t)(130 + w * 64 + nl - (quad >> 1)) * 48
                    + (quad & 1) * 16;
#pragma unroll 4
  for (int sc = 0; sc < 65; ++sc) {
    short8 a = af[sc * 64 + lane];
    const char* xb = xb0 - 96 * sc;
    acc0 = __builtin_amdgcn_mfma_f32_16x16x32_bf16(a, *(const short8*)(xb       ), acc0, 0, 0, 0);
    acc1 = __builtin_amdgcn_mfma_f32_16x16x32_bf16(a, *(const short8*)(xb +  768), acc1, 0, 0, 0);
    acc2 = __builtin_amdgcn_mfma_f32_16x16x32_bf16(a, *(const short8*)(xb + 1536), acc2, 0, 0, 0);
    acc3 = __builtin_amdgcn_mfma_f32_16x16x32_bf16(a, *(const short8*)(xb + 2304), acc3, 0, 0, 0);
  }
  float* hp = H + (size_t)rx * NS + 16 * (n0 + w * 64 + nl) + quad * 4;
#pragma unroll
  for (int i = 0; i < 4; ++i) {
    hp[i]       = acc0[i] * scale;
    hp[256 + i] = acc1[i] * scale;
    hp[512 + i] = acc2[i] * scale;
    hp[768 + i] = acc3[i] * scale;
  }
}

// ---------------- K5: cs output = sum_e (spikes (*) imp)
__global__ __launch_bounds__(256) void k5_cs(
    const float* __restrict__ imp, const float* __restrict__ fv, float* __restrict__ out)
{
  int r = blockIdx.y;
  int t = blockIdx.x * 256 + threadIdx.x;
  int q = t >> 10, sl = t & 1023;
  float i1 = imp[r * 2048 + sl];
  float i2 = (q >= 1) ? imp[r * 2048 + 1024 + sl] : 0.f;
  float s = 0.f;
#pragma unroll
  for (int e = 0; e < 4; ++e) {
    float f1 = fv[(e * 16 + r) * 128 + q];
    float f2 = (q >= 1) ? fv[(e * 16 + r) * 128 + q - 1] : 0.f;
    s += f1 * i1 + f2 * i2;
  }
  out[532480 + (size_t)r * NS + t] = s;
}

// ---------------- K6: 128-tap stride conv via MFMA Toeplitz GEMM + deform mix + tanh reduce
__global__ __launch_bounds__(256) void k6_mfma(
    const float* __restrict__ H, const float* __restrict__ imp,
    const unsigned short* __restrict__ abf2,
    const float* __restrict__ wsf, float* __restrict__ out)
{
  int r = blockIdx.y;
  int n0 = blockIdx.x * 64;
  int rm = r & 3, rq = r >> 2;
  int tid = threadIdx.x;
  int w = tid >> 6, lane = tid & 63;
  int quad = lane >> 4, n = lane & 15;
  int col = n0 + w * 16 + n;               // t' in [0,1024)

  __shared__ float fvs[4][128];
  for (int i = tid; i < 512; i += 256)
    fvs[i >> 7][i & 127] = wsf[OFF_FV + ((i >> 7) * 16 + r) * 128 + (i & 127)];
  __syncthreads();

  // B-frags from global H (line-coalesced strided loads), bf16 in regs
  short8 bf0[4], bf1[4];
  const float* H0 = H + (size_t)(2 * r) * NS + col;
  const float* H1 = H + (size_t)(2 * r + 1) * NS + col;
#pragma unroll
  for (int kt = 0; kt < 4; ++kt) {
#pragma unroll
    for (int j = 0; j < 8; ++j) {
      int p = kt * 32 + quad * 8 + j;
      bf0[kt][j] = (short)f2bf(H0[(size_t)p * 1024]);
      bf1[kt][j] = (short)f2bf(H1[(size_t)p * 1024]);
    }
  }

  // deformation weights per (mt,i), e-invariant
  float d0r[8][4];
  const float* dwg = wsf + OFF_DW;
#pragma unroll
  for (int mt = 0; mt < 8; ++mt)
#pragma unroll
    for (int i = 0; i < 4; ++i) {
      int q = mt * 16 + quad * 4 + i;
      d0r[mt][i] = dwg[q * 1024 + col];
    }

  float impA = imp[r * 2048 + col];
  float impB = imp[r * 2048 + 1024 + col];
  float mix0r = wsf[OFF_MIX0 + r];

  float tansum[8][4];
#pragma unroll
  for (int mt = 0; mt < 8; ++mt)
#pragma unroll
    for (int i = 0; i < 4; ++i) tansum[mt][i] = 0.f;

  const short8* af = (const short8*)abf2;
  for (int e = 0; e < 4; ++e) {
    float ge = wsf[OFF_GABS + 4 * e + rq];
    const short8* afe = af + ((size_t)(r * 4 + e) * 32) * 64 + lane;
#pragma unroll
    for (int mt = 0; mt < 8; ++mt) {
      floatx4 acc0 = {0, 0, 0, 0}, acc1 = {0, 0, 0, 0};
#pragma unroll
      for (int kt = 0; kt < 4; ++kt) {
        short8 a = afe[(mt * 4 + kt) * 64];
        acc0 = __builtin_amdgcn_mfma_f32_16x16x32_bf16(a, bf0[kt], acc0, 0, 0, 0);
        acc1 = __builtin_amdgcn_mfma_f32_16x16x32_bf16(a, bf1[kt], acc1, 0, 0, 0);
      }
#pragma unroll
      for (int i = 0; i < 4; ++i) {
        int q = mt * 16 + quad * 4 + i;
        float fq = fvs[e][q];
        float fqm = (q > 0) ? fvs[e][q - 1] : 0.f;
        float rsv = fq * impA + fqm * impB;
        float d0 = d0r[mt][i];
        float conv = d0 * acc0[i] + (1.0f - d0) * acc1[i];
        float z = (mix0r * rsv + conv) * ge;
        float e2 = __expf(2.0f * z);
        tansum[mt][i] += 1.0f - 2.0f / (e2 + 1.0f);
      }
    }
  }
#pragma unroll
  for (int mt = 0; mt < 8; ++mt)
#pragma unroll
    for (int i = 0; i < 4; ++i) {
      int q = mt * 16 + quad * 4 + i;
      atomicAdd(&out[(size_t)rm * NS + q * 1024 + col], tansum[mt][i]);
    }
}

extern "C" void kernel_launch(void* const* d_in, const int* in_sizes, int n_in,
                              void* d_out, int out_size, void* d_ws, size_t ws_size,
                              hipStream_t stream) {
  const float* csig   = (const float*)d_in[0];
  const float* deform = (const float*)d_in[1];
  const float* aem    = (const float*)d_in[2];
  const float* aes    = (const float*)d_in[3];
  const float* aea    = (const float*)d_in[4];
  const float* aep    = (const float*)d_in[5];
  const float* aeo    = (const float*)d_in[6];
  const float* ddmp   = (const float*)d_in[7];
  const float* dmas   = (const float*)d_in[8];
  const float* dten   = (const float*)d_in[9];
  const float* ddisp  = (const float*)d_in[10];
  const float* damp   = (const float*)d_in[11];
  const float* infl   = (const float*)d_in[12];
  const float* smix   = (const float*)d_in[13];
  const float* router = (const float*)d_in[14];
  const float* lmix   = (const float*)d_in[15];
  const float* gains  = (const float*)d_in[16];
  const float* anoise = (const float*)d_in[17];

  float*  wsf = (float*)d_ws;
  double* wsd = (double*)((char*)d_ws + (size_t)WSF_COUNT * 4);
  unsigned short* resb = (unsigned short*)d_ws;
  unsigned short* abf  = (unsigned short*)d_ws + AFRAG_USH;
  unsigned short* abf2 = (unsigned short*)d_ws + ABF2_USH;
  float*  out = (float*)d_out;

  hipMemsetAsync(d_out, 0, (size_t)524288 * 4, stream);

  k0_prep<<<512, 256, 0, stream>>>(csig, deform, ddmp, dmas, dten, ddisp, damp,
                                   infl, smix, router, lmix, gains, wsf, wsd, out);
  k1_dho<<<dim3(512, 32), 256, 0, stream>>>(wsf, wsd, resb, wsf + OFF_PART);
  k1r_reduce<<<32, 256, 0, stream>>>(wsf + OFF_PART, wsf + OFF_NORM);
  k2_gauss<<<8, 256, 0, stream>>>(aem, aes, aea, aep, wsf + OFF_VG, wsf + OFF_GSS);
  k3_imp<<<dim3(8, 16), 256, 0, stream>>>(wsf + OFF_VG, wsf + OFF_GSS, aeo, anoise,
                                          wsf + OFF_IMP);
  kA_frag<<<260, 256, 0, stream>>>(wsf + OFF_IMP, abf);
  kA2_frag<<<512, 256, 0, stream>>>(wsf, abf2);
  k4_mfma<<<dim3(32, 32), 256, 0, stream>>>(resb, abf, wsf + OFF_NORM, wsf,
                                            wsf + OFF_H);
  k5_cs<<<dim3(512, 16), 256, 0, stream>>>(wsf + OFF_IMP, wsf + OFF_FV, out);
  k6_mfma<<<dim3(16, 16), 256, 0, stream>>>(wsf + OFF_H, wsf + OFF_IMP, abf2, wsf, out);
}

// Round 5
// 203.115 us; speedup vs baseline: 5.4250x; 1.1457x over previous
//
#include <hip/hip_runtime.h>
#include <math.h>

#define NS 131072
#define EPSF 1e-8f

// workspace float offsets
#define OFF_RES    0u        // ushort res_bf[32][131072] = ushort idx 0..4194304
#define OFF_H      4194304u  // 32*131072 H[rx][t] (f32)
#define OFF_IMP    8388608u  // 16*2048
#define OFF_VG     8421376u  // 8*2048
#define OFF_DW     8437760u  // 131072 deformation ch0 weight
#define OFF_FV     8568832u  // 4*16*128 routed frames
#define OFF_NORM   8577024u  // 32 res sumsq
#define OFF_GSS    8577056u  // 8 gauss sumsq
#define OFF_MIX0   8577064u  // 16
#define OFF_MIX1   8577080u  // 16
#define OFF_GABS   8577096u  // 16
#define OFF_W3     8577112u  // 32*3 stack softmax
#define OFF_PF     8577208u  // 32*32 osc params (see k0)
#define OFF_PART   8578560u  // 32*512 per-block norm partials

#define AFRAG_USH  4194304u  // ushort offset: imp A-frags [16 r][65 sc][64 lane][8]
#define ABF2_USH   4726784u  // ushort offset: fv-Toeplitz A-frags [16r][4e][8mt][4kt][64][8]

typedef __attribute__((ext_vector_type(8))) short short8;
typedef __attribute__((ext_vector_type(4))) float floatx4;
typedef __attribute__((ext_vector_type(4))) unsigned short ushort4v;

#define INV2PI 0.15915494309189535f

__device__ __forceinline__ float sigmf(float x) { return 1.0f / (1.0f + expf(-x)); }

__device__ __forceinline__ unsigned short f2bf(float x) {
  unsigned u = __float_as_uint(x);
  unsigned r = (u + 0x7FFFu + ((u >> 16) & 1u)) >> 16;
  return (unsigned short)r;
}

// ---------------- K0: dw weights (all blocks) + block0: fv/before, mixes, gains, stack w, osc params
// pf layout (stride 32 per rx):
//  [0..6)  negGam = -gamma
//  [6..12) Ap = amp*x0
//  [12..18) gamAp = gamma*amp*x0
//  [18..24) cinfl = infl*ln(10)   (0 for block 0)
//  [24..26) B1p = amp*gamma*x0/omega  (block 0, f64-derived)
//  [26..28) omr1 = omega/(2pi)        (block 0, f64-derived)
//  [28..32) Wf   = 10^tension/mass    (blocks 1-2, oscs 2..5)
__global__ __launch_bounds__(256) void k0_prep(
    const float* __restrict__ csig, const float* __restrict__ deform,
    const float* __restrict__ ddmp, const float* __restrict__ dmas,
    const float* __restrict__ dten, const float* __restrict__ ddisp,
    const float* __restrict__ damp, const float* __restrict__ infl,
    const float* __restrict__ smix, const float* __restrict__ router,
    const float* __restrict__ lmix, const float* __restrict__ gains,
    float* __restrict__ wsf, float* __restrict__ out)
{
  int tid = threadIdx.x;
  int t = blockIdx.x * 256 + tid;
  { // deformation softmax + linear interp weight for channel 0
    float src = (t + 0.5f) * (1.0f / 1024.0f) - 0.5f;
    src = fminf(fmaxf(src, 0.0f), 127.0f);
    int lo = (int)src;
    int hi = min(lo + 1, 127);
    float w = src - (float)lo;
    float c0l = 1.0f / (1.0f + expf(deform[128 + lo] - (1.0f + deform[lo])));
    float c0h = 1.0f / (1.0f + expf(deform[128 + hi] - (1.0f + deform[hi])));
    wsf[OFF_DW + t] = c0l * (1.0f - w) + c0h * w;
  }
  if (blockIdx.x == 0) {
    for (int idx = tid; idx < 8192; idx += 256) {   // fv = einsum('becf,cr')
      int e = idx >> 11, r = (idx >> 7) & 15, f = idx & 127;
      float s = 0.f;
      for (int c = 0; c < 16; ++c) s += csig[(e * 16 + c) * 128 + f] * router[c * 16 + r];
      wsf[OFF_FV + idx] = s;
      out[524288 + idx] = s;   // 'before' output
    }
    if (tid < 16) {
      int r = tid;
      float l0 = lmix[r * 2], l1 = lmix[r * 2 + 1];
      float m = fmaxf(l0, l1);
      float e0 = expf(l0 - m), e1 = expf(l1 - m), inv = 1.0f / (e0 + e1);
      wsf[OFF_MIX0 + r] = e0 * inv;
      wsf[OFF_MIX1 + r] = e1 * inv;
      wsf[OFF_GABS + r] = fabsf(gains[r]);
    }
    if (tid < 32) {
      int rx = tid, r = rx >> 1, x = rx & 1;
      float a0 = smix[rx * 3], a1 = smix[rx * 3 + 1], a2 = smix[rx * 3 + 2];
      float mm = fmaxf(a0, fmaxf(a1, a2));
      float e0 = expf(a0 - mm), e1 = expf(a1 - mm), e2 = expf(a2 - mm);
      float inv = 1.0f / (e0 + e1 + e2);
      wsf[OFF_W3 + rx * 3 + 0] = e0 * inv;
      wsf[OFF_W3 + rx * 3 + 1] = e1 * inv;
      wsf[OFF_W3 + rx * 3 + 2] = e2 * inv;
      float* pf = wsf + OFF_PF + rx * 32;
      for (int ent = 0; ent < 6; ++ent) {
        int b = ent >> 1, o = ent & 1;
        int id = ((b * 2 + o) * 16 + r) * 2 + x;
        float mass = 2.0f * sigmf(dmas[id]);
        float dampg = 30.0f * sigmf(ddmp[id]);
        float gam = dampg / (2.0f * mass);
        double W = exp((double)dten[id] * 2.302585092994046) / (double)mass;
        float x0v = ddisp[id];
        float ampv = damp[id];
        float infv = 0.f;
        if (b == 1) infv = infl[(o * 16 + r) * 2 + x];
        if (b == 2) infv = infl[((2 + o) * 16 + r) * 2 + x];
        pf[0 + ent]  = -gam;
        pf[6 + ent]  = ampv * x0v;
        pf[12 + ent] = gam * ampv * x0v;
        pf[18 + ent] = infv * 2.3025851f;
        if (b == 0) {
          double om = sqrt(W - (double)gam * (double)gam);
          pf[24 + o] = (float)((double)(gam * x0v * ampv) / om);
          pf[26 + o] = (float)(om * 0.15915494309189535);
        } else {
          pf[28 + ent - 2] = (float)W;
        }
      }
    }
  }
}

// ---------------- K1: DHO chain (all-f32, HW transcendentals) -> res bf16 + norm partials
__global__ __launch_bounds__(256) void k1_dho(const float* __restrict__ wsf,
    unsigned short* __restrict__ resb, float* __restrict__ partials)
{
  int rx = blockIdx.y;
  int t = blockIdx.x * 256 + threadIdx.x;
  const float* pf = wsf + OFF_PF + rx * 32;
  float ttf = (float)t * (10.0f / 131071.0f);

  float o1v = 0.f;
#pragma unroll
  for (int o = 0; o < 2; ++o) {
    float fr = pf[26 + o] * ttf;
    fr -= rintf(fr);
    float sn = __builtin_amdgcn_sinf(fr);
    float cn = __builtin_amdgcn_cosf(fr);
    float ex = __expf(pf[o] * ttf);
    o1v += ex * (pf[6 + o] * cn + pf[24 + o] * sn);
  }
  float prev = o1v, o2v = 0.f, o3v = 0.f;
#pragma unroll
  for (int blk = 1; blk < 3; ++blk) {
    float acc = 0.f;
#pragma unroll
    for (int oo = 0; oo < 2; ++oo) {
      int o = blk * 2 + oo;
      float ng = pf[o];
      float p10 = __expf(prev * pf[18 + o]);
      float rad = __builtin_fmaf(pf[28 + o - 2], p10, -(ng * ng));
      float om = __builtin_amdgcn_sqrtf(rad);
      float fr = (om * INV2PI) * ttf;
      fr -= rintf(fr);
      float sn = __builtin_amdgcn_sinf(fr);
      float cn = __builtin_amdgcn_cosf(fr);
      float Bp = pf[12 + o] * __builtin_amdgcn_rcpf(om);
      float ex = __expf(ng * ttf);
      acc += ex * (pf[6 + o] * cn + Bp * sn);
    }
    if (blk == 1) o2v = acc; else o3v = acc;
    prev = acc;
  }
  const float* w3 = wsf + OFF_W3 + rx * 3;
  float rv = w3[0] * o1v + w3[1] * o2v + w3[2] * o3v;
  resb[(size_t)rx * NS + t] = f2bf(rv);

  __shared__ float bred[4];
  float sq = rv * rv;
#pragma unroll
  for (int off = 32; off; off >>= 1) sq += __shfl_down(sq, off, 64);
  if ((threadIdx.x & 63) == 0) bred[threadIdx.x >> 6] = sq;
  __syncthreads();
  if (threadIdx.x == 0)
    partials[rx * 512 + blockIdx.x] = bred[0] + bred[1] + bred[2] + bred[3];
}

// ---------------- K1r: reduce 512 partials per rx -> norm_acc[rx]
__global__ __launch_bounds__(256) void k1r_reduce(const float* __restrict__ partials,
                                                 float* __restrict__ norm_acc)
{
  int rx = blockIdx.x;
  int tid = threadIdx.x;
  __shared__ float bred[4];
  float s = partials[rx * 512 + tid] + partials[rx * 512 + 256 + tid];
#pragma unroll
  for (int off = 32; off; off >>= 1) s += __shfl_down(s, off, 64);
  if ((tid & 63) == 0) bred[tid >> 6] = s;
  __syncthreads();
  if (tid == 0) norm_acc[rx] = bred[0] + bred[1] + bred[2] + bred[3];
}

// ---------------- K2: gamma-pdf gaussian stacks
__global__ __launch_bounds__(256) void k2_gauss(
    const float* __restrict__ means, const float* __restrict__ stds,
    const float* __restrict__ amps, const float* __restrict__ pos,
    float* __restrict__ vg, float* __restrict__ gss)
{
  int g = blockIdx.x;
  int tid = threadIdx.x;
  __shared__ float kS[16], rateS[16], logAS[16], aS[16];
  __shared__ int dS[16];
  __shared__ float red[4];
  if (tid < 16) {
    int c = tid, idx = c * 8 + g;
    double m = fabs((double)means[idx]);
    double s = fabs((double)stds[idx]);
    double k = m / (s + 1e-8); k = k * k;
    double rate = m / (s * s + 1e-8);
    double logA = k * log(rate + 1e-8) - lgamma(k);
    kS[c] = (float)k; rateS[c] = (float)rate; logAS[c] = (float)logA;
    aS[c] = fabsf(amps[idx]);
    int d = 0;
    for (int l = 0; l < 11; ++l) {
      float p0 = pos[(idx * 11 + l) * 2], p1 = pos[(idx * 11 + l) * 2 + 1];
      d = d * 2 + (p1 > p0 ? 1 : 0);
    }
    dS[c] = d;
  }
  __syncthreads();
  const float step = (float)((1.0 - 1e-8) / 2047.0);
  float sumsq = 0.f;
  for (int i = tid; i < 2048; i += 256) {
    float v = 0.f;
    for (int c = 0; c < 16; ++c) {
      int mi = i - dS[c];
      if (mi >= 0) {
        float tm = 1e-8f + (float)mi * step;
        float lp = logAS[c] + (kS[c] - 1.0f) * __logf(tm) - rateS[c] * tm;
        v += aS[c] * __expf(lp);
      }
    }
    vg[g * 2048 + i] = v;
    sumsq += v * v;
  }
#pragma unroll
  for (int off = 32; off; off >>= 1) sumsq += __shfl_down(sumsq, off, 64);
  if ((tid & 63) == 0) red[tid >> 6] = sumsq;
  __syncthreads();
  if (tid == 0) gss[g] = red[0] + red[1] + red[2] + red[3];
}

// ---------------- K3: impulse = overall_amp[c] * sum_g unitnorm(v_g) * noise
__global__ __launch_bounds__(256) void k3_imp(
    const float* __restrict__ vg, const float* __restrict__ gss,
    const float* __restrict__ ovamp, const float* __restrict__ noise,
    float* __restrict__ imp)
{
  int c = blockIdx.y;
  int i = blockIdx.x * 256 + threadIdx.x;
  float S = 0.f;
#pragma unroll
  for (int g = 0; g < 8; ++g) S += vg[g * 2048 + i] / (sqrtf(gss[g]) + EPSF);
  imp[c * 2048 + i] = ovamp[c] * S * noise[c * 2048 + i];
}

// ---------------- KA: build MFMA A-fragments of the block-Toeplitz imp matrix (for k4)
__global__ __launch_bounds__(256) void kA_frag(
    const float* __restrict__ imp, unsigned short* __restrict__ abf)
{
  int gid = blockIdx.x * 256 + threadIdx.x;   // 16*65*64 = 66560
  if (gid >= 66560) return;
  int r = gid / (65 * 64);
  int rem = gid % (65 * 64);
  int sc = rem >> 6, lane = rem & 63;
  int m = lane & 15, quad = lane >> 4;
  int qp = (quad < 2) ? quad : quad - 4;
  int base = 32 * sc + m - 8 * qp;
  short8 v;
#pragma unroll
  for (int j = 0; j < 8; ++j) {
    int idx = base - j;
    unsigned short b = 0;
    if (idx >= 0 && idx < 2048) b = f2bf(imp[r * 2048 + idx]);
    v[j] = (short)b;
  }
  *(short8*)&abf[(size_t)gid * 8] = v;
}

// ---------------- KA2: build MFMA A-fragments of the fv-Toeplitz matrix (for k6)
__global__ __launch_bounds__(256) void kA2_frag(
    const float* __restrict__ wsf, unsigned short* __restrict__ abf2)
{
  int gid = blockIdx.x * 256 + threadIdx.x;   // 131072
  int lane = gid & 63;
  int kt = (gid >> 6) & 3;
  int mt = (gid >> 8) & 7;
  int e  = (gid >> 11) & 3;
  int r  = (gid >> 13) & 15;
  int m = lane & 15, quad = lane >> 4;
  int base = mt * 16 + m - kt * 32 - quad * 8;
  const float* fve = wsf + OFF_FV + (e * 16 + r) * 128;
  short8 v;
#pragma unroll
  for (int j = 0; j < 8; ++j) {
    int f = base - j;
    unsigned short b = 0;
    if (f >= 0 && f < 128) b = f2bf(fve[f]);
    v[j] = (short)b;
  }
  *(short8*)&abf2[(size_t)gid * 8] = v;
}

// ---------------- K4: H via MFMA block-Toeplitz: H[:,n] = sum_s G_s X[:,n-s]
__global__ __launch_bounds__(256) void k4_mfma(
    const unsigned short* __restrict__ resb, const unsigned short* __restrict__ abf,
    const float* __restrict__ norm_acc, const float* __restrict__ wsf,
    float* __restrict__ H)
{
  int rx = blockIdx.y, r = rx >> 1;
  int n0 = blockIdx.x * 256;                       // 256 columns of 16 samples
  __shared__ __align__(16) unsigned short Xs[9280]; // 386 cols x stride 24
  int tid = threadIdx.x;
  for (int i = tid; i < 1544; i += 256) {          // 386*16/4 ushort4 chunks
    int q_rel = i >> 2, p4 = (i & 3) * 4;
    int q = n0 - 130 + q_rel;
    ushort4v v = {0, 0, 0, 0};
    if (q >= 0) v = *(const ushort4v*)&resb[(size_t)rx * NS + q * 16 + p4];
    *(ushort4v*)&Xs[q_rel * 24 + p4] = v;
  }
  __syncthreads();
  int lane = tid & 63, w = tid >> 6;
  int quad = lane >> 4, nl = lane & 15;
  float n1 = sqrtf(norm_acc[rx]);
  float s1 = 1.0f / (n1 + EPSF);
  float scale = s1 * (1.0f / (n1 * s1 + EPSF)) * wsf[OFF_MIX1 + r];
  const short8* af = (const short8*)(abf) + (size_t)r * 65 * 64;
  floatx4 acc0 = {0,0,0,0}, acc1 = {0,0,0,0}, acc2 = {0,0,0,0}, acc3 = {0,0,0,0};
  const char* xb0 = (const char*)Xs + (size_t)(130 + w * 64 + nl - (quad >> 1)) * 48
                    + (quad & 1) * 16;
#pragma unroll 4
  for (int sc = 0; sc < 65; ++sc) {
    short8 a = af[sc * 64 + lane];
    const char* xb = xb0 - 96 * sc;
    acc0 = __builtin_amdgcn_mfma_f32_16x16x32_bf16(a, *(const short8*)(xb       ), acc0, 0, 0, 0);
    acc1 = __builtin_amdgcn_mfma_f32_16x16x32_bf16(a, *(const short8*)(xb +  768), acc1, 0, 0, 0);
    acc2 = __builtin_amdgcn_mfma_f32_16x16x32_bf16(a, *(const short8*)(xb + 1536), acc2, 0, 0, 0);
    acc3 = __builtin_amdgcn_mfma_f32_16x16x32_bf16(a, *(const short8*)(xb + 2304), acc3, 0, 0, 0);
  }
  float* hp = H + (size_t)rx * NS + 16 * (n0 + w * 64 + nl) + quad * 4;
#pragma unroll
  for (int i = 0; i < 4; ++i) {
    hp[i]       = acc0[i] * scale;
    hp[256 + i] = acc1[i] * scale;
    hp[512 + i] = acc2[i] * scale;
    hp[768 + i] = acc3[i] * scale;
  }
}

// ---------------- K5: cs output = sum_e (spikes (*) imp)
__global__ __launch_bounds__(256) void k5_cs(
    const float* __restrict__ imp, const float* __restrict__ fv, float* __restrict__ out)
{
  int r = blockIdx.y;
  int t = blockIdx.x * 256 + threadIdx.x;
  int q = t >> 10, sl = t & 1023;
  float i1 = imp[r * 2048 + sl];
  float i2 = (q >= 1) ? imp[r * 2048 + 1024 + sl] : 0.f;
  float s = 0.f;
#pragma unroll
  for (int e = 0; e < 4; ++e) {
    float f1 = fv[(e * 16 + r) * 128 + q];
    float f2 = (q >= 1) ? fv[(e * 16 + r) * 128 + q - 1] : 0.f;
    s += f1 * i1 + f2 * i2;
  }
  out[532480 + (size_t)r * NS + t] = s;
}

// ---------------- K6: 128-tap stride conv via MFMA Toeplitz GEMM + deform mix + tanh reduce
__global__ __launch_bounds__(256) void k6_mfma(
    const float* __restrict__ H, const float* __restrict__ imp,
    const unsigned short* __restrict__ abf2,
    const float* __restrict__ wsf, float* __restrict__ out)
{
  int r = blockIdx.y;
  int n0 = blockIdx.x * 64;
  int rm = r & 3, rq = r >> 2;
  int tid = threadIdx.x;
  int w = tid >> 6, lane = tid & 63;
  int quad = lane >> 4, n = lane & 15;
  int col = n0 + w * 16 + n;               // t' in [0,1024)

  __shared__ float fvs[4][128];
  for (int i = tid; i < 512; i += 256)
    fvs[i >> 7][i & 127] = wsf[OFF_FV + ((i >> 7) * 16 + r) * 128 + (i & 127)];
  __syncthreads();

  short8 bf0[4], bf1[4];
  const float* H0 = H + (size_t)(2 * r) * NS + col;
  const float* H1 = H + (size_t)(2 * r + 1) * NS + col;
#pragma unroll
  for (int kt = 0; kt < 4; ++kt) {
#pragma unroll
    for (int j = 0; j < 8; ++j) {
      int p = kt * 32 + quad * 8 + j;
      bf0[kt][j] = (short)f2bf(H0[(size_t)p * 1024]);
      bf1[kt][j] = (short)f2bf(H1[(size_t)p * 1024]);
    }
  }

  float d0r[8][4];
  const float* dwg = wsf + OFF_DW;
#pragma unroll
  for (int mt = 0; mt < 8; ++mt)
#pragma unroll
    for (int i = 0; i < 4; ++i) {
      int q = mt * 16 + quad * 4 + i;
      d0r[mt][i] = dwg[q * 1024 + col];
    }

  float impA = imp[r * 2048 + col];
  float impB = imp[r * 2048 + 1024 + col];
  float mix0r = wsf[OFF_MIX0 + r];

  float tansum[8][4];
#pragma unroll
  for (int mt = 0; mt < 8; ++mt)
#pragma unroll
    for (int i = 0; i < 4; ++i) tansum[mt][i] = 0.f;

  const short8* af = (const short8*)abf2;
  for (int e = 0; e < 4; ++e) {
    float ge = wsf[OFF_GABS + 4 * e + rq];
    const short8* afe = af + ((size_t)(r * 4 + e) * 32) * 64 + lane;
#pragma unroll
    for (int mt = 0; mt < 8; ++mt) {
      floatx4 acc0 = {0, 0, 0, 0}, acc1 = {0, 0, 0, 0};
#pragma unroll
      for (int kt = 0; kt < 4; ++kt) {
        short8 a = afe[(mt * 4 + kt) * 64];
        acc0 = __builtin_amdgcn_mfma_f32_16x16x32_bf16(a, bf0[kt], acc0, 0, 0, 0);
        acc1 = __builtin_amdgcn_mfma_f32_16x16x32_bf16(a, bf1[kt], acc1, 0, 0, 0);
      }
#pragma unroll
      for (int i = 0; i < 4; ++i) {
        int q = mt * 16 + quad * 4 + i;
        float fq = fvs[e][q];
        float fqm = (q > 0) ? fvs[e][q - 1] : 0.f;
        float rsv = fq * impA + fqm * impB;
        float d0 = d0r[mt][i];
        float conv = d0 * acc0[i] + (1.0f - d0) * acc1[i];
        float z = (mix0r * rsv + conv) * ge;
        float e2 = __expf(2.0f * z);
        tansum[mt][i] += 1.0f - 2.0f / (e2 + 1.0f);
      }
    }
  }
#pragma unroll
  for (int mt = 0; mt < 8; ++mt)
#pragma unroll
    for (int i = 0; i < 4; ++i) {
      int q = mt * 16 + quad * 4 + i;
      atomicAdd(&out[(size_t)rm * NS + q * 1024 + col], tansum[mt][i]);
    }
}

extern "C" void kernel_launch(void* const* d_in, const int* in_sizes, int n_in,
                              void* d_out, int out_size, void* d_ws, size_t ws_size,
                              hipStream_t stream) {
  const float* csig   = (const float*)d_in[0];
  const float* deform = (const float*)d_in[1];
  const float* aem    = (const float*)d_in[2];
  const float* aes    = (const float*)d_in[3];
  const float* aea    = (const float*)d_in[4];
  const float* aep    = (const float*)d_in[5];
  const float* aeo    = (const float*)d_in[6];
  const float* ddmp   = (const float*)d_in[7];
  const float* dmas   = (const float*)d_in[8];
  const float* dten   = (const float*)d_in[9];
  const float* ddisp  = (const float*)d_in[10];
  const float* damp   = (const float*)d_in[11];
  const float* infl   = (const float*)d_in[12];
  const float* smix   = (const float*)d_in[13];
  const float* router = (const float*)d_in[14];
  const float* lmix   = (const float*)d_in[15];
  const float* gains  = (const float*)d_in[16];
  const float* anoise = (const float*)d_in[17];

  float*  wsf = (float*)d_ws;
  unsigned short* resb = (unsigned short*)d_ws;
  unsigned short* abf  = (unsigned short*)d_ws + AFRAG_USH;
  unsigned short* abf2 = (unsigned short*)d_ws + ABF2_USH;
  float*  out = (float*)d_out;

  hipMemsetAsync(d_out, 0, (size_t)524288 * 4, stream);

  k0_prep<<<512, 256, 0, stream>>>(csig, deform, ddmp, dmas, dten, ddisp, damp,
                                   infl, smix, router, lmix, gains, wsf, out);
  k1_dho<<<dim3(512, 32), 256, 0, stream>>>(wsf, resb, wsf + OFF_PART);
  k1r_reduce<<<32, 256, 0, stream>>>(wsf + OFF_PART, wsf + OFF_NORM);
  k2_gauss<<<8, 256, 0, stream>>>(aem, aes, aea, aep, wsf + OFF_VG, wsf + OFF_GSS);
  k3_imp<<<dim3(8, 16), 256, 0, stream>>>(wsf + OFF_VG, wsf + OFF_GSS, aeo, anoise,
                                          wsf + OFF_IMP);
  kA_frag<<<260, 256, 0, stream>>>(wsf + OFF_IMP, abf);
  kA2_frag<<<512, 256, 0, stream>>>(wsf, abf2);
  k4_mfma<<<dim3(32, 32), 256, 0, stream>>>(resb, abf, wsf + OFF_NORM, wsf,
                                            wsf + OFF_H);
  k5_cs<<<dim3(512, 16), 256, 0, stream>>>(wsf + OFF_IMP, wsf + OFF_FV, out);
  k6_mfma<<<dim3(16, 16), 256, 0, stream>>>(wsf + OFF_H, wsf + OFF_IMP, abf2, wsf, out);
}

// Round 6
// 195.811 us; speedup vs baseline: 5.6274x; 1.0373x over previous
//
#include <hip/hip_runtime.h>
#include <math.h>

#define NS 131072
#define EPSF 1e-8f

// workspace float offsets
#define OFF_H      4194304u  // 32*131072 H[rx][t] (f32)
#define OFF_IMP    8388608u  // 16*2048
#define OFF_VG     8421376u  // 8*2048
#define OFF_DW     8437760u  // 131072 deformation ch0 weight
#define OFF_FV     8568832u  // 4*16*128 routed frames
#define OFF_NORM   8577024u  // 32 res sumsq
#define OFF_GSS    8577056u  // 8 gauss sumsq
#define OFF_MIX0   8577064u  // 16
#define OFF_MIX1   8577080u  // 16
#define OFF_GABS   8577096u  // 16
#define OFF_W3     8577112u  // 32*3 stack softmax
#define OFF_PF     8577208u  // 32*32 osc params (see k0)
#define OFF_PART   8578560u  // 32*512 per-block norm partials

#define AFRAG_USH  4194304u  // ushort offset: imp A-frags [16 r][65 sc][64 lane][8]
#define ABF2_USH   4726784u  // ushort offset: fv-Toeplitz A-frags [16r][4e][8mt][4kt][64][8]

typedef __attribute__((ext_vector_type(8))) short short8;
typedef __attribute__((ext_vector_type(4))) float floatx4;
typedef __attribute__((ext_vector_type(4))) unsigned short ushort4v;

#define INV2PI 0.15915494309189535f

__device__ __forceinline__ float sigmf(float x) { return 1.0f / (1.0f + expf(-x)); }

__device__ __forceinline__ unsigned short f2bf(float x) {
  unsigned u = __float_as_uint(x);
  unsigned r = (u + 0x7FFFu + ((u >> 16) & 1u)) >> 16;
  return (unsigned short)r;
}

// ---------------- K0: dw weights + zero out-sum region (all blocks);
// block0: fv/before, mixes, gains, stack w, osc params, zero gss
__global__ __launch_bounds__(256) void k0_prep(
    const float* __restrict__ csig, const float* __restrict__ deform,
    const float* __restrict__ ddmp, const float* __restrict__ dmas,
    const float* __restrict__ dten, const float* __restrict__ ddisp,
    const float* __restrict__ damp, const float* __restrict__ infl,
    const float* __restrict__ smix, const float* __restrict__ router,
    const float* __restrict__ lmix, const float* __restrict__ gains,
    float* __restrict__ wsf, float* __restrict__ out)
{
  int tid = threadIdx.x;
  int t = blockIdx.x * 256 + tid;
  { // zero the atomically-accumulated output region (4 floats/thread)
    float4 z = {0.f, 0.f, 0.f, 0.f};
    *(float4*)&out[(size_t)t * 4] = z;
  }
  { // deformation softmax + linear interp weight for channel 0
    float src = (t + 0.5f) * (1.0f / 1024.0f) - 0.5f;
    src = fminf(fmaxf(src, 0.0f), 127.0f);
    int lo = (int)src;
    int hi = min(lo + 1, 127);
    float w = src - (float)lo;
    float c0l = 1.0f / (1.0f + expf(deform[128 + lo] - (1.0f + deform[lo])));
    float c0h = 1.0f / (1.0f + expf(deform[128 + hi] - (1.0f + deform[hi])));
    wsf[OFF_DW + t] = c0l * (1.0f - w) + c0h * w;
  }
  if (blockIdx.x == 0) {
    for (int idx = tid; idx < 8192; idx += 256) {   // fv = einsum('becf,cr')
      int e = idx >> 11, r = (idx >> 7) & 15, f = idx & 127;
      float s = 0.f;
      for (int c = 0; c < 16; ++c) s += csig[(e * 16 + c) * 128 + f] * router[c * 16 + r];
      wsf[OFF_FV + idx] = s;
      out[524288 + idx] = s;   // 'before' output
    }
    if (tid < 8) wsf[OFF_GSS + tid] = 0.f;
    if (tid < 16) {
      int r = tid;
      float l0 = lmix[r * 2], l1 = lmix[r * 2 + 1];
      float m = fmaxf(l0, l1);
      float e0 = expf(l0 - m), e1 = expf(l1 - m), inv = 1.0f / (e0 + e1);
      wsf[OFF_MIX0 + r] = e0 * inv;
      wsf[OFF_MIX1 + r] = e1 * inv;
      wsf[OFF_GABS + r] = fabsf(gains[r]);
    }
    if (tid < 32) {
      int rx = tid, r = rx >> 1, x = rx & 1;
      float a0 = smix[rx * 3], a1 = smix[rx * 3 + 1], a2 = smix[rx * 3 + 2];
      float mm = fmaxf(a0, fmaxf(a1, a2));
      float e0 = expf(a0 - mm), e1 = expf(a1 - mm), e2 = expf(a2 - mm);
      float inv = 1.0f / (e0 + e1 + e2);
      wsf[OFF_W3 + rx * 3 + 0] = e0 * inv;
      wsf[OFF_W3 + rx * 3 + 1] = e1 * inv;
      wsf[OFF_W3 + rx * 3 + 2] = e2 * inv;
      float* pf = wsf + OFF_PF + rx * 32;
      for (int ent = 0; ent < 6; ++ent) {
        int b = ent >> 1, o = ent & 1;
        int id = ((b * 2 + o) * 16 + r) * 2 + x;
        float mass = 2.0f * sigmf(dmas[id]);
        float dampg = 30.0f * sigmf(ddmp[id]);
        float gam = dampg / (2.0f * mass);
        double W = exp((double)dten[id] * 2.302585092994046) / (double)mass;
        float x0v = ddisp[id];
        float ampv = damp[id];
        float infv = 0.f;
        if (b == 1) infv = infl[(o * 16 + r) * 2 + x];
        if (b == 2) infv = infl[((2 + o) * 16 + r) * 2 + x];
        pf[0 + ent]  = -gam;
        pf[6 + ent]  = ampv * x0v;
        pf[12 + ent] = gam * ampv * x0v;
        pf[18 + ent] = infv * 2.3025851f;
        if (b == 0) {
          double om = sqrt(W - (double)gam * (double)gam);
          pf[24 + o] = (float)((double)(gam * x0v * ampv) / om);
          pf[26 + o] = (float)(om * 0.15915494309189535);
        } else {
          pf[28 + ent - 2] = (float)W;
        }
      }
    }
  }
}

// ---------------- K1: DHO chain (all-f32, HW transcendentals) -> res bf16 + norm partials
__global__ __launch_bounds__(256) void k1_dho(const float* __restrict__ wsf,
    unsigned short* __restrict__ resb, float* __restrict__ partials)
{
  int rx = blockIdx.y;
  int t = blockIdx.x * 256 + threadIdx.x;
  const float* pf = wsf + OFF_PF + rx * 32;
  float ttf = (float)t * (10.0f / 131071.0f);

  float o1v = 0.f;
#pragma unroll
  for (int o = 0; o < 2; ++o) {
    float fr = pf[26 + o] * ttf;
    fr -= rintf(fr);
    float sn = __builtin_amdgcn_sinf(fr);
    float cn = __builtin_amdgcn_cosf(fr);
    float ex = __expf(pf[o] * ttf);
    o1v += ex * (pf[6 + o] * cn + pf[24 + o] * sn);
  }
  float prev = o1v, o2v = 0.f, o3v = 0.f;
#pragma unroll
  for (int blk = 1; blk < 3; ++blk) {
    float acc = 0.f;
#pragma unroll
    for (int oo = 0; oo < 2; ++oo) {
      int o = blk * 2 + oo;
      float ng = pf[o];
      float p10 = __expf(prev * pf[18 + o]);
      float rad = __builtin_fmaf(pf[28 + o - 2], p10, -(ng * ng));
      float om = __builtin_amdgcn_sqrtf(rad);
      float fr = (om * INV2PI) * ttf;
      fr -= rintf(fr);
      float sn = __builtin_amdgcn_sinf(fr);
      float cn = __builtin_amdgcn_cosf(fr);
      float Bp = pf[12 + o] * __builtin_amdgcn_rcpf(om);
      float ex = __expf(ng * ttf);
      acc += ex * (pf[6 + o] * cn + Bp * sn);
    }
    if (blk == 1) o2v = acc; else o3v = acc;
    prev = acc;
  }
  const float* w3 = wsf + OFF_W3 + rx * 3;
  float rv = w3[0] * o1v + w3[1] * o2v + w3[2] * o3v;
  resb[(size_t)rx * NS + t] = f2bf(rv);

  __shared__ float bred[4];
  float sq = rv * rv;
#pragma unroll
  for (int off = 32; off; off >>= 1) sq += __shfl_down(sq, off, 64);
  if ((threadIdx.x & 63) == 0) bred[threadIdx.x >> 6] = sq;
  __syncthreads();
  if (threadIdx.x == 0)
    partials[rx * 512 + blockIdx.x] = bred[0] + bred[1] + bred[2] + bred[3];
}

// ---------------- K12: blocks 0-63 = gamma-pdf gauss (8 g x 8 tiles);
//                  blocks 64-95 = norm partial reduce
__global__ __launch_bounds__(256) void k12_gauss_reduce(
    const float* __restrict__ means, const float* __restrict__ stds,
    const float* __restrict__ amps, const float* __restrict__ pos,
    const float* __restrict__ partials,
    float* __restrict__ vg, float* __restrict__ gss, float* __restrict__ norm_acc)
{
  int bid = blockIdx.x;
  int tid = threadIdx.x;
  __shared__ float kS[16], rateS[16], logAS[16], aS[16];
  __shared__ int dS[16];
  __shared__ float red[4];
  if (bid >= 64) {                       // k1r: reduce 512 partials per rx
    int rx = bid - 64;
    float s = partials[rx * 512 + tid] + partials[rx * 512 + 256 + tid];
#pragma unroll
    for (int off = 32; off; off >>= 1) s += __shfl_down(s, off, 64);
    if ((tid & 63) == 0) red[tid >> 6] = s;
    __syncthreads();
    if (tid == 0) norm_acc[rx] = red[0] + red[1] + red[2] + red[3];
    return;
  }
  int g = bid >> 3;
  int i = (bid & 7) * 256 + tid;
  if (tid < 16) {
    int c = tid, idx = c * 8 + g;
    double m = fabs((double)means[idx]);
    double s = fabs((double)stds[idx]);
    double k = m / (s + 1e-8); k = k * k;
    double rate = m / (s * s + 1e-8);
    double logA = k * log(rate + 1e-8) - lgamma(k);
    kS[c] = (float)k; rateS[c] = (float)rate; logAS[c] = (float)logA;
    aS[c] = fabsf(amps[idx]);
    int d = 0;
    for (int l = 0; l < 11; ++l) {
      float p0 = pos[(idx * 11 + l) * 2], p1 = pos[(idx * 11 + l) * 2 + 1];
      d = d * 2 + (p1 > p0 ? 1 : 0);
    }
    dS[c] = d;
  }
  __syncthreads();
  const float step = (float)((1.0 - 1e-8) / 2047.0);
  float v = 0.f;
  for (int c = 0; c < 16; ++c) {
    int mi = i - dS[c];
    if (mi >= 0) {
      float tm = 1e-8f + (float)mi * step;
      float lp = logAS[c] + (kS[c] - 1.0f) * __logf(tm) - rateS[c] * tm;
      v += aS[c] * __expf(lp);
    }
  }
  vg[g * 2048 + i] = v;
  float sumsq = v * v;
#pragma unroll
  for (int off = 32; off; off >>= 1) sumsq += __shfl_down(sumsq, off, 64);
  if ((tid & 63) == 0) red[tid >> 6] = sumsq;
  __syncthreads();
  if (tid == 0) atomicAdd(&gss[g], red[0] + red[1] + red[2] + red[3]);
}

// ---------------- K3: impulse = overall_amp[c] * sum_g unitnorm(v_g) * noise
__global__ __launch_bounds__(256) void k3_imp(
    const float* __restrict__ vg, const float* __restrict__ gss,
    const float* __restrict__ ovamp, const float* __restrict__ noise,
    float* __restrict__ imp)
{
  int c = blockIdx.y;
  int i = blockIdx.x * 256 + threadIdx.x;
  float S = 0.f;
#pragma unroll
  for (int g = 0; g < 8; ++g) S += vg[g * 2048 + i] / (sqrtf(gss[g]) + EPSF);
  imp[c * 2048 + i] = ovamp[c] * S * noise[c * 2048 + i];
}

// ---------------- KAA: merged A-fragment builders (kA2: blocks<512, kA: blocks>=512)
__global__ __launch_bounds__(256) void kAA_frag(
    const float* __restrict__ imp, const float* __restrict__ wsf,
    unsigned short* __restrict__ abf, unsigned short* __restrict__ abf2)
{
  int bid = blockIdx.x;
  int tid = threadIdx.x;
  if (bid < 512) {                        // fv-Toeplitz frags for k6
    int gid = bid * 256 + tid;            // 131072
    int lane = gid & 63;
    int kt = (gid >> 6) & 3;
    int mt = (gid >> 8) & 7;
    int e  = (gid >> 11) & 3;
    int r  = (gid >> 13) & 15;
    int m = lane & 15, quad = lane >> 4;
    int base = mt * 16 + m - kt * 32 - quad * 8;
    const float* fve = wsf + OFF_FV + (e * 16 + r) * 128;
    short8 v;
#pragma unroll
    for (int j = 0; j < 8; ++j) {
      int f = base - j;
      unsigned short b = 0;
      if (f >= 0 && f < 128) b = f2bf(fve[f]);
      v[j] = (short)b;
    }
    *(short8*)&abf2[(size_t)gid * 8] = v;
  } else {                                // imp block-Toeplitz frags for k4
    int gid = (bid - 512) * 256 + tid;    // 16*65*64 = 66560
    if (gid >= 66560) return;
    int r = gid / (65 * 64);
    int rem = gid % (65 * 64);
    int sc = rem >> 6, lane = rem & 63;
    int m = lane & 15, quad = lane >> 4;
    int qp = (quad < 2) ? quad : quad - 4;
    int base = 32 * sc + m - 8 * qp;
    short8 v;
#pragma unroll
    for (int j = 0; j < 8; ++j) {
      int idx = base - j;
      unsigned short b = 0;
      if (idx >= 0 && idx < 2048) b = f2bf(imp[r * 2048 + idx]);
      v[j] = (short)b;
    }
    *(short8*)&abf[(size_t)gid * 8] = v;
  }
}

// ---------------- K4: H via MFMA block-Toeplitz with rolling B-frag register window
__global__ __launch_bounds__(256) void k4_mfma(
    const unsigned short* __restrict__ resb, const unsigned short* __restrict__ abf,
    const float* __restrict__ norm_acc, const float* __restrict__ wsf,
    float* __restrict__ H)
{
  int rx = blockIdx.y, r = rx >> 1;
  int n0 = blockIdx.x * 256;                       // 256 columns of 16 samples
  __shared__ __align__(16) unsigned short Xs[9280]; // 386 cols x stride 24
  int tid = threadIdx.x;
  for (int i = tid; i < 1544; i += 256) {          // 386*16/4 ushort4 chunks
    int q_rel = i >> 2, p4 = (i & 3) * 4;
    int q = n0 - 130 + q_rel;
    ushort4v v = {0, 0, 0, 0};
    if (q >= 0) v = *(const ushort4v*)&resb[(size_t)rx * NS + q * 16 + p4];
    *(ushort4v*)&Xs[q_rel * 24 + p4] = v;
  }
  __syncthreads();
  int lane = tid & 63, w = tid >> 6;
  int quad = lane >> 4, nl = lane & 15;
  float n1 = sqrtf(norm_acc[rx]);
  float s1 = 1.0f / (n1 + EPSF);
  float scale = s1 * (1.0f / (n1 * s1 + EPSF)) * wsf[OFF_MIX1 + r];
  const short8* af = (const short8*)(abf) + (size_t)r * 65 * 64 + lane;
  floatx4 acc0 = {0,0,0,0}, acc1 = {0,0,0,0}, acc2 = {0,0,0,0}, acc3 = {0,0,0,0};
  const char* xbase = (const char*)Xs + (size_t)(130 + w * 64 + nl - (quad >> 1)) * 48
                      + (quad & 1) * 16;
  // frag(sc, g) = mem[xbase - 96*(sc - 8g)]; rolling window of 25 registers
  short8 wbuf[25];
#pragma unroll
  for (int s = -24; s < 0; ++s)
    wbuf[s + 25] = *(const short8*)(xbase - 96 * s);
#pragma unroll
  for (int sc = 0; sc < 65; ++sc) {
    wbuf[sc % 25] = *(const short8*)(xbase - 96 * sc);
    short8 a = af[sc * 64];
    acc0 = __builtin_amdgcn_mfma_f32_16x16x32_bf16(a, wbuf[sc % 25],        acc0, 0, 0, 0);
    acc1 = __builtin_amdgcn_mfma_f32_16x16x32_bf16(a, wbuf[(sc + 17) % 25], acc1, 0, 0, 0);
    acc2 = __builtin_amdgcn_mfma_f32_16x16x32_bf16(a, wbuf[(sc + 9) % 25],  acc2, 0, 0, 0);
    acc3 = __builtin_amdgcn_mfma_f32_16x16x32_bf16(a, wbuf[(sc + 1) % 25],  acc3, 0, 0, 0);
  }
  float* hp = H + (size_t)rx * NS + 16 * (n0 + w * 64 + nl) + quad * 4;
#pragma unroll
  for (int i = 0; i < 4; ++i) {
    hp[i]       = acc0[i] * scale;
    hp[256 + i] = acc1[i] * scale;
    hp[512 + i] = acc2[i] * scale;
    hp[768 + i] = acc3[i] * scale;
  }
}

// ---------------- K6: 128-tap stride conv via MFMA + deform mix + tanh reduce + cs (fused k5)
__global__ __launch_bounds__(256) void k6_mfma(
    const float* __restrict__ H, const float* __restrict__ imp,
    const unsigned short* __restrict__ abf2,
    const float* __restrict__ wsf, float* __restrict__ out)
{
  int r = blockIdx.y;
  int n0 = blockIdx.x * 32;
  int rm = r & 3, rq = r >> 2;
  int tid = threadIdx.x;
  int w = tid >> 6, lane = tid & 63;
  int wc = w & 1, wm = w >> 1;             // col half, mt half
  int quad = lane >> 4, n = lane & 15;
  int col = n0 + wc * 16 + n;              // t' in [0,1024)

  __shared__ float fvs[4][128];
  for (int i = tid; i < 512; i += 256)
    fvs[i >> 7][i & 127] = wsf[OFF_FV + ((i >> 7) * 16 + r) * 128 + (i & 127)];
  __syncthreads();

  short8 bf0[4], bf1[4];
  const float* H0 = H + (size_t)(2 * r) * NS + col;
  const float* H1 = H + (size_t)(2 * r + 1) * NS + col;
#pragma unroll
  for (int kt = 0; kt < 4; ++kt) {
#pragma unroll
    for (int j = 0; j < 8; ++j) {
      int p = kt * 32 + quad * 8 + j;
      bf0[kt][j] = (short)f2bf(H0[(size_t)p * 1024]);
      bf1[kt][j] = (short)f2bf(H1[(size_t)p * 1024]);
    }
  }

  float d0r[4][4];
  const float* dwg = wsf + OFF_DW;
#pragma unroll
  for (int mi = 0; mi < 4; ++mi)
#pragma unroll
    for (int i = 0; i < 4; ++i) {
      int q = (wm * 4 + mi) * 16 + quad * 4 + i;
      d0r[mi][i] = dwg[q * 1024 + col];
    }

  float impA = imp[r * 2048 + col];
  float impB = imp[r * 2048 + 1024 + col];
  float mix0r = wsf[OFF_MIX0 + r];

  float tansum[4][4], csum[4][4];
#pragma unroll
  for (int mi = 0; mi < 4; ++mi)
#pragma unroll
    for (int i = 0; i < 4; ++i) { tansum[mi][i] = 0.f; csum[mi][i] = 0.f; }

  const short8* af = (const short8*)abf2;
  for (int e = 0; e < 4; ++e) {
    float ge = wsf[OFF_GABS + 4 * e + rq];
    const short8* afe = af + ((size_t)(r * 4 + e) * 32) * 64 + lane;
#pragma unroll
    for (int mi = 0; mi < 4; ++mi) {
      int mt = wm * 4 + mi;
      floatx4 acc0 = {0, 0, 0, 0}, acc1 = {0, 0, 0, 0};
#pragma unroll
      for (int kt = 0; kt < 4; ++kt) {
        short8 a = afe[(mt * 4 + kt) * 64];
        acc0 = __builtin_amdgcn_mfma_f32_16x16x32_bf16(a, bf0[kt], acc0, 0, 0, 0);
        acc1 = __builtin_amdgcn_mfma_f32_16x16x32_bf16(a, bf1[kt], acc1, 0, 0, 0);
      }
#pragma unroll
      for (int i = 0; i < 4; ++i) {
        int q = mt * 16 + quad * 4 + i;
        float fq = fvs[e][q];
        float fqm = (q > 0) ? fvs[e][q - 1] : 0.f;
        float rsv = fq * impA + fqm * impB;
        csum[mi][i] += rsv;
        float d0 = d0r[mi][i];
        float conv = d0 * acc0[i] + (1.0f - d0) * acc1[i];
        float z = (mix0r * rsv + conv) * ge;
        float e2 = __expf(2.0f * z);
        tansum[mi][i] += 1.0f - 2.0f / (e2 + 1.0f);
      }
    }
  }
#pragma unroll
  for (int mi = 0; mi < 4; ++mi)
#pragma unroll
    for (int i = 0; i < 4; ++i) {
      int q = (wm * 4 + mi) * 16 + quad * 4 + i;
      atomicAdd(&out[(size_t)rm * NS + q * 1024 + col], tansum[mi][i]);
      out[532480 + (size_t)r * NS + q * 1024 + col] = csum[mi][i];
    }
}

extern "C" void kernel_launch(void* const* d_in, const int* in_sizes, int n_in,
                              void* d_out, int out_size, void* d_ws, size_t ws_size,
                              hipStream_t stream) {
  const float* csig   = (const float*)d_in[0];
  const float* deform = (const float*)d_in[1];
  const float* aem    = (const float*)d_in[2];
  const float* aes    = (const float*)d_in[3];
  const float* aea    = (const float*)d_in[4];
  const float* aep    = (const float*)d_in[5];
  const float* aeo    = (const float*)d_in[6];
  const float* ddmp   = (const float*)d_in[7];
  const float* dmas   = (const float*)d_in[8];
  const float* dten   = (const float*)d_in[9];
  const float* ddisp  = (const float*)d_in[10];
  const float* damp   = (const float*)d_in[11];
  const float* infl   = (const float*)d_in[12];
  const float* smix   = (const float*)d_in[13];
  const float* router = (const float*)d_in[14];
  const float* lmix   = (const float*)d_in[15];
  const float* gains  = (const float*)d_in[16];
  const float* anoise = (const float*)d_in[17];

  float*  wsf = (float*)d_ws;
  unsigned short* resb = (unsigned short*)d_ws;
  unsigned short* abf  = (unsigned short*)d_ws + AFRAG_USH;
  unsigned short* abf2 = (unsigned short*)d_ws + ABF2_USH;
  float*  out = (float*)d_out;

  k0_prep<<<512, 256, 0, stream>>>(csig, deform, ddmp, dmas, dten, ddisp, damp,
                                   infl, smix, router, lmix, gains, wsf, out);
  k1_dho<<<dim3(512, 32), 256, 0, stream>>>(wsf, resb, wsf + OFF_PART);
  k12_gauss_reduce<<<96, 256, 0, stream>>>(aem, aes, aea, aep, wsf + OFF_PART,
                                           wsf + OFF_VG, wsf + OFF_GSS,
                                           wsf + OFF_NORM);
  k3_imp<<<dim3(8, 16), 256, 0, stream>>>(wsf + OFF_VG, wsf + OFF_GSS, aeo, anoise,
                                          wsf + OFF_IMP);
  kAA_frag<<<772, 256, 0, stream>>>(wsf + OFF_IMP, wsf, abf, abf2);
  k4_mfma<<<dim3(32, 32), 256, 0, stream>>>(resb, abf, wsf + OFF_NORM, wsf,
                                            wsf + OFF_H);
  k6_mfma<<<dim3(32, 16), 256, 0, stream>>>(wsf + OFF_H, wsf + OFF_IMP, abf2, wsf, out);
}

// Round 7
// 176.845 us; speedup vs baseline: 6.2309x; 1.1072x over previous
//
#include <hip/hip_runtime.h>
#include <math.h>

#define NS 131072
#define EPSF 1e-8f

// workspace float offsets
#define OFF_IMP    8388608u  // 16*2048
#define OFF_VG     8421376u  // 8*2048
#define OFF_DW     8437760u  // 131072 deformation ch0 weight
#define OFF_FV     8568832u  // 4*16*128 routed frames
#define OFF_NORM   8577024u  // 32 res sumsq
#define OFF_MIX0   8577064u  // 16
#define OFF_MIX1   8577080u  // 16
#define OFF_GABS   8577096u  // 16
#define OFF_W3     8577112u  // 32*3 stack softmax
#define OFF_PF     8577208u  // 32*32 osc params (see k0)
#define OFF_PART   8578560u  // 32*512 per-block norm partials
#define OFF_GSSP   8594944u  // 8*8 gauss sumsq partials

// ushort offsets
#define AFRAG_USH  4194304u  // imp A-frags [16 r][65 sc][64 lane][8]
#define ABF2_USH   4726784u  // fv-Toeplitz A-frags [16r][4e][8mt][4kt][64][8]
#define HB_USH     8388608u  // H bf16 [32 rx][131072]

typedef __attribute__((ext_vector_type(8))) short short8;
typedef __attribute__((ext_vector_type(4))) float floatx4;
typedef __attribute__((ext_vector_type(4))) unsigned short ushort4v;

#define INV2PI 0.15915494309189535f

__device__ __forceinline__ float sigmf(float x) { return 1.0f / (1.0f + expf(-x)); }

__device__ __forceinline__ unsigned short f2bf(float x) {
  unsigned u = __float_as_uint(x);
  unsigned r = (u + 0x7FFFu + ((u >> 16) & 1u)) >> 16;
  return (unsigned short)r;
}

// ---------------- A: blocks<512: zero out-sum, dw weights, abf2 frags (fv recomputed in LDS);
//                  block0 extra: mixes/gains/stack/osc params; blocks 512-575: gauss -> gss partials
__global__ __launch_bounds__(256) void kA_prep(
    const float* __restrict__ csig, const float* __restrict__ deform,
    const float* __restrict__ ddmp, const float* __restrict__ dmas,
    const float* __restrict__ dten, const float* __restrict__ ddisp,
    const float* __restrict__ damp, const float* __restrict__ infl,
    const float* __restrict__ smix, const float* __restrict__ router,
    const float* __restrict__ lmix, const float* __restrict__ gains,
    const float* __restrict__ means, const float* __restrict__ stds,
    const float* __restrict__ amps, const float* __restrict__ pos,
    float* __restrict__ wsf, unsigned short* __restrict__ abf2,
    float* __restrict__ out)
{
  int tid = threadIdx.x;
  int bid = blockIdx.x;
  if (bid < 512) {
    int t = bid * 256 + tid;
    { // zero the atomically-accumulated output region
      float4 z = {0.f, 0.f, 0.f, 0.f};
      *(float4*)&out[(size_t)t * 4] = z;
    }
    { // deformation softmax + interp weight ch0
      float src = (t + 0.5f) * (1.0f / 1024.0f) - 0.5f;
      src = fminf(fmaxf(src, 0.0f), 127.0f);
      int lo = (int)src;
      int hi = min(lo + 1, 127);
      float w = src - (float)lo;
      float c0l = 1.0f / (1.0f + expf(deform[128 + lo] - (1.0f + deform[lo])));
      float c0h = 1.0f / (1.0f + expf(deform[128 + hi] - (1.0f + deform[hi])));
      wsf[OFF_DW + t] = c0l * (1.0f - w) + c0h * w;
    }
    // abf2: block has fixed (mt,e,r); fv row in LDS
    int mt = bid & 7, e = (bid >> 3) & 3, r = (bid >> 5) & 15;
    __shared__ float fvrow[128];
    if (tid < 128) {
      float s = 0.f;
      for (int c = 0; c < 16; ++c)
        s += csig[(e * 16 + c) * 128 + tid] * router[c * 16 + r];
      fvrow[tid] = s;
      if (mt == 0) {
        wsf[OFF_FV + (e * 16 + r) * 128 + tid] = s;
        out[524288 + (e * 16 + r) * 128 + tid] = s;   // 'before'
      }
    }
    __syncthreads();
    {
      int gid = bid * 256 + tid;
      int lane = gid & 63;
      int kt = (gid >> 6) & 3;
      int m = lane & 15, quad = lane >> 4;
      int base = mt * 16 + m - kt * 32 - quad * 8;
      short8 v;
#pragma unroll
      for (int j = 0; j < 8; ++j) {
        int f = base - j;
        unsigned short b = 0;
        if (f >= 0 && f < 128) b = f2bf(fvrow[f]);
        v[j] = (short)b;
      }
      *(short8*)&abf2[(size_t)gid * 8] = v;
    }
    if (bid == 0) {
      if (tid < 16) {
        int r2 = tid;
        float l0 = lmix[r2 * 2], l1 = lmix[r2 * 2 + 1];
        float mx = fmaxf(l0, l1);
        float e0 = expf(l0 - mx), e1 = expf(l1 - mx), inv = 1.0f / (e0 + e1);
        wsf[OFF_MIX0 + r2] = e0 * inv;
        wsf[OFF_MIX1 + r2] = e1 * inv;
        wsf[OFF_GABS + r2] = fabsf(gains[r2]);
      }
      if (tid < 32) {
        int rx = tid, r2 = rx >> 1, x = rx & 1;
        float a0 = smix[rx * 3], a1 = smix[rx * 3 + 1], a2 = smix[rx * 3 + 2];
        float mm = fmaxf(a0, fmaxf(a1, a2));
        float e0 = expf(a0 - mm), e1 = expf(a1 - mm), e2 = expf(a2 - mm);
        float inv = 1.0f / (e0 + e1 + e2);
        wsf[OFF_W3 + rx * 3 + 0] = e0 * inv;
        wsf[OFF_W3 + rx * 3 + 1] = e1 * inv;
        wsf[OFF_W3 + rx * 3 + 2] = e2 * inv;
        float* pf = wsf + OFF_PF + rx * 32;
        for (int ent = 0; ent < 6; ++ent) {
          int b = ent >> 1, o = ent & 1;
          int id = ((b * 2 + o) * 16 + r2) * 2 + x;
          float mass = 2.0f * sigmf(dmas[id]);
          float dampg = 30.0f * sigmf(ddmp[id]);
          float gam = dampg / (2.0f * mass);
          double W = exp((double)dten[id] * 2.302585092994046) / (double)mass;
          float x0v = ddisp[id];
          float ampv = damp[id];
          float infv = 0.f;
          if (b == 1) infv = infl[(o * 16 + r2) * 2 + x];
          if (b == 2) infv = infl[((2 + o) * 16 + r2) * 2 + x];
          pf[0 + ent]  = -gam;
          pf[6 + ent]  = ampv * x0v;
          pf[12 + ent] = gam * ampv * x0v;
          pf[18 + ent] = infv * 2.3025851f;
          if (b == 0) {
            double om = sqrt(W - (double)gam * (double)gam);
            pf[24 + o] = (float)((double)(gam * x0v * ampv) / om);
            pf[26 + o] = (float)(om * 0.15915494309189535);
          } else {
            pf[28 + ent - 2] = (float)W;
          }
        }
      }
    }
  } else {                               // gauss: 64 blocks
    int gb = bid - 512;
    int g = gb >> 3;
    int i = (gb & 7) * 256 + tid;
    __shared__ float kS[16], rateS[16], logAS[16], aS[16];
    __shared__ int dS[16];
    __shared__ float red[4];
    if (tid < 16) {
      int c = tid, idx = c * 8 + g;
      double m = fabs((double)means[idx]);
      double s = fabs((double)stds[idx]);
      double k = m / (s + 1e-8); k = k * k;
      double rate = m / (s * s + 1e-8);
      double logA = k * log(rate + 1e-8) - lgamma(k);
      kS[c] = (float)k; rateS[c] = (float)rate; logAS[c] = (float)logA;
      aS[c] = fabsf(amps[idx]);
      int d = 0;
      for (int l = 0; l < 11; ++l) {
        float p0 = pos[(idx * 11 + l) * 2], p1 = pos[(idx * 11 + l) * 2 + 1];
        d = d * 2 + (p1 > p0 ? 1 : 0);
      }
      dS[c] = d;
    }
    __syncthreads();
    const float step = (float)((1.0 - 1e-8) / 2047.0);
    float v = 0.f;
    for (int c = 0; c < 16; ++c) {
      int mi = i - dS[c];
      if (mi >= 0) {
        float tm = 1e-8f + (float)mi * step;
        float lp = logAS[c] + (kS[c] - 1.0f) * __logf(tm) - rateS[c] * tm;
        v += aS[c] * __expf(lp);
      }
    }
    wsf[OFF_VG + g * 2048 + i] = v;
    float sumsq = v * v;
#pragma unroll
    for (int off = 32; off; off >>= 1) sumsq += __shfl_down(sumsq, off, 64);
    if ((tid & 63) == 0) red[tid >> 6] = sumsq;
    __syncthreads();
    if (tid == 0) wsf[OFF_GSSP + gb] = red[0] + red[1] + red[2] + red[3];
  }
}

// ---------------- K1: DHO chain (all-f32, HW transcendentals) -> res bf16 + norm partials
__global__ __launch_bounds__(256) void k1_dho(const float* __restrict__ wsf,
    unsigned short* __restrict__ resb, float* __restrict__ partials)
{
  int rx = blockIdx.y;
  int t = blockIdx.x * 256 + threadIdx.x;
  const float* pf = wsf + OFF_PF + rx * 32;
  float ttf = (float)t * (10.0f / 131071.0f);

  float o1v = 0.f;
#pragma unroll
  for (int o = 0; o < 2; ++o) {
    float fr = pf[26 + o] * ttf;
    fr -= rintf(fr);
    float sn = __builtin_amdgcn_sinf(fr);
    float cn = __builtin_amdgcn_cosf(fr);
    float ex = __expf(pf[o] * ttf);
    o1v += ex * (pf[6 + o] * cn + pf[24 + o] * sn);
  }
  float prev = o1v, o2v = 0.f, o3v = 0.f;
#pragma unroll
  for (int blk = 1; blk < 3; ++blk) {
    float acc = 0.f;
#pragma unroll
    for (int oo = 0; oo < 2; ++oo) {
      int o = blk * 2 + oo;
      float ng = pf[o];
      float p10 = __expf(prev * pf[18 + o]);
      float rad = __builtin_fmaf(pf[28 + o - 2], p10, -(ng * ng));
      float om = __builtin_amdgcn_sqrtf(rad);
      float fr = (om * INV2PI) * ttf;
      fr -= rintf(fr);
      float sn = __builtin_amdgcn_sinf(fr);
      float cn = __builtin_amdgcn_cosf(fr);
      float Bp = pf[12 + o] * __builtin_amdgcn_rcpf(om);
      float ex = __expf(ng * ttf);
      acc += ex * (pf[6 + o] * cn + Bp * sn);
    }
    if (blk == 1) o2v = acc; else o3v = acc;
    prev = acc;
  }
  const float* w3 = wsf + OFF_W3 + rx * 3;
  float rv = w3[0] * o1v + w3[1] * o2v + w3[2] * o3v;
  resb[(size_t)rx * NS + t] = f2bf(rv);

  __shared__ float bred[4];
  float sq = rv * rv;
#pragma unroll
  for (int off = 32; off; off >>= 1) sq += __shfl_down(sq, off, 64);
  if ((threadIdx.x & 63) == 0) bred[threadIdx.x >> 6] = sq;
  __syncthreads();
  if (threadIdx.x == 0)
    partials[rx * 512 + blockIdx.x] = bred[0] + bred[1] + bred[2] + bred[3];
}

// ---------------- B: blocks 0-31 norm reduce; 32-159 impulse; 160-419 abf frags (imp inline)
__global__ __launch_bounds__(256) void kB_mid(
    const float* __restrict__ ovamp, const float* __restrict__ noise,
    float* __restrict__ wsf, unsigned short* __restrict__ abf)
{
  int bid = blockIdx.x;
  int tid = threadIdx.x;
  if (bid < 32) {                        // norm reduce
    int rx = bid;
    const float* partials = wsf + OFF_PART;
    __shared__ float red[4];
    float s = partials[rx * 512 + tid] + partials[rx * 512 + 256 + tid];
#pragma unroll
    for (int off = 32; off; off >>= 1) s += __shfl_down(s, off, 64);
    if ((tid & 63) == 0) red[tid >> 6] = s;
    __syncthreads();
    if (tid == 0) wsf[OFF_NORM + rx] = red[0] + red[1] + red[2] + red[3];
    return;
  }
  __shared__ float wS[8];
  if (tid < 8) {
    float g8 = 0.f;
#pragma unroll
    for (int u = 0; u < 8; ++u) g8 += wsf[OFF_GSSP + tid * 8 + u];
    wS[tid] = 1.0f / (sqrtf(g8) + EPSF);
  }
  __syncthreads();
  const float* vg = wsf + OFF_VG;
  if (bid < 160) {                       // impulse
    int idx0 = bid - 32;
    int c = idx0 >> 3;
    int i = (idx0 & 7) * 256 + tid;
    float S = 0.f;
#pragma unroll
    for (int g = 0; g < 8; ++g) S += vg[g * 2048 + i] * wS[g];
    wsf[OFF_IMP + c * 2048 + i] = ovamp[c] * S * noise[c * 2048 + i];
    return;
  }
  // abf: imp recomputed inline
  int gid = (bid - 160) * 256 + tid;     // 16*65*64 = 66560
  if (gid >= 66560) return;
  int r = gid / (65 * 64);
  int rem = gid % (65 * 64);
  int sc = rem >> 6, lane = rem & 63;
  int m = lane & 15, quad = lane >> 4;
  int qp = (quad < 2) ? quad : quad - 4;
  int base = 32 * sc + m - 8 * qp;
  float oa = ovamp[r];
  short8 v;
#pragma unroll
  for (int j = 0; j < 8; ++j) {
    int idx = base - j;
    unsigned short b = 0;
    if (idx >= 0 && idx < 2048) {
      float S = 0.f;
#pragma unroll
      for (int g = 0; g < 8; ++g) S += vg[g * 2048 + idx] * wS[g];
      b = f2bf(oa * S * noise[r * 2048 + idx]);
    }
    v[j] = (short)b;
  }
  *(short8*)&abf[(size_t)gid * 8] = v;
}

// ---------------- K4: H via MFMA block-Toeplitz, rolling B-frag window; H stored bf16
__global__ __launch_bounds__(256) void k4_mfma(
    const unsigned short* __restrict__ resb, const unsigned short* __restrict__ abf,
    const float* __restrict__ wsf, unsigned short* __restrict__ Hb)
{
  int rx = blockIdx.y, r = rx >> 1;
  int n0 = blockIdx.x * 256;                       // 256 columns of 16 samples
  __shared__ __align__(16) unsigned short Xs[9280]; // 386 cols x stride 24
  int tid = threadIdx.x;
  for (int i = tid; i < 772; i += 256) {           // 16B chunks
    int q_rel = i >> 1, p8 = (i & 1) * 8;
    int q = n0 - 130 + q_rel;
    short8 v = {0, 0, 0, 0, 0, 0, 0, 0};
    if (q >= 0) v = *(const short8*)&resb[(size_t)rx * NS + q * 16 + p8];
    *(short8*)&Xs[q_rel * 24 + p8] = v;
  }
  __syncthreads();
  int lane = tid & 63, w = tid >> 6;
  int quad = lane >> 4, nl = lane & 15;
  float n1 = sqrtf(wsf[OFF_NORM + rx]);
  float s1 = 1.0f / (n1 + EPSF);
  float scale = s1 * (1.0f / (n1 * s1 + EPSF)) * wsf[OFF_MIX1 + r];
  const short8* af = (const short8*)(abf) + (size_t)r * 65 * 64 + lane;
  floatx4 acc0 = {0,0,0,0}, acc1 = {0,0,0,0}, acc2 = {0,0,0,0}, acc3 = {0,0,0,0};
  const char* xbase = (const char*)Xs + (size_t)(130 + w * 64 + nl - (quad >> 1)) * 48
                      + (quad & 1) * 16;
  short8 wbuf[25];
#pragma unroll
  for (int s = -24; s < 0; ++s)
    wbuf[s + 25] = *(const short8*)(xbase - 96 * s);
#pragma unroll
  for (int sc = 0; sc < 65; ++sc) {
    wbuf[sc % 25] = *(const short8*)(xbase - 96 * sc);
    short8 a = af[sc * 64];
    acc0 = __builtin_amdgcn_mfma_f32_16x16x32_bf16(a, wbuf[sc % 25],        acc0, 0, 0, 0);
    acc1 = __builtin_amdgcn_mfma_f32_16x16x32_bf16(a, wbuf[(sc + 17) % 25], acc1, 0, 0, 0);
    acc2 = __builtin_amdgcn_mfma_f32_16x16x32_bf16(a, wbuf[(sc + 9) % 25],  acc2, 0, 0, 0);
    acc3 = __builtin_amdgcn_mfma_f32_16x16x32_bf16(a, wbuf[(sc + 1) % 25],  acc3, 0, 0, 0);
  }
  unsigned short* hp = Hb + (size_t)rx * NS + 16 * (n0 + w * 64 + nl) + quad * 4;
  ushort4v h0, h1, h2, h3;
#pragma unroll
  for (int i = 0; i < 4; ++i) {
    h0[i] = f2bf(acc0[i] * scale);
    h1[i] = f2bf(acc1[i] * scale);
    h2[i] = f2bf(acc2[i] * scale);
    h3[i] = f2bf(acc3[i] * scale);
  }
  *(ushort4v*)(hp)       = h0;
  *(ushort4v*)(hp + 256) = h1;
  *(ushort4v*)(hp + 512) = h2;
  *(ushort4v*)(hp + 768) = h3;
}

// ---------------- K6: 128-tap stride conv via MFMA + deform mix + tanh reduce + cs
__global__ __launch_bounds__(256) void k6_mfma(
    const unsigned short* __restrict__ Hb, const float* __restrict__ imp,
    const unsigned short* __restrict__ abf2,
    const float* __restrict__ wsf, float* __restrict__ out)
{
  int r = blockIdx.y;
  int n0 = blockIdx.x * 32;
  int rm = r & 3, rq = r >> 2;
  int tid = threadIdx.x;
  int w = tid >> 6, lane = tid & 63;
  int wc = w & 1, wm = w >> 1;
  int quad = lane >> 4, n = lane & 15;
  int col = n0 + wc * 16 + n;              // t' in [0,1024)

  __shared__ float fvs[4][128];
  for (int i = tid; i < 512; i += 256)
    fvs[i >> 7][i & 127] = wsf[OFF_FV + ((i >> 7) * 16 + r) * 128 + (i & 127)];
  __syncthreads();

  short8 bf0[4], bf1[4];
  const unsigned short* H0 = Hb + (size_t)(2 * r) * NS + col;
  const unsigned short* H1 = Hb + (size_t)(2 * r + 1) * NS + col;
#pragma unroll
  for (int kt = 0; kt < 4; ++kt) {
#pragma unroll
    for (int j = 0; j < 8; ++j) {
      int p = kt * 32 + quad * 8 + j;
      bf0[kt][j] = (short)H0[(size_t)p * 1024];
      bf1[kt][j] = (short)H1[(size_t)p * 1024];
    }
  }

  float d0r[4][4];
  const float* dwg = wsf + OFF_DW;
#pragma unroll
  for (int mi = 0; mi < 4; ++mi)
#pragma unroll
    for (int i = 0; i < 4; ++i) {
      int q = (wm * 4 + mi) * 16 + quad * 4 + i;
      d0r[mi][i] = dwg[q * 1024 + col];
    }

  float impA = imp[r * 2048 + col];
  float impB = imp[r * 2048 + 1024 + col];
  float mix0r = wsf[OFF_MIX0 + r];

  float tansum[4][4], csum[4][4];
#pragma unroll
  for (int mi = 0; mi < 4; ++mi)
#pragma unroll
    for (int i = 0; i < 4; ++i) { tansum[mi][i] = 0.f; csum[mi][i] = 0.f; }

  const short8* af = (const short8*)abf2;
  for (int e = 0; e < 4; ++e) {
    float ge = wsf[OFF_GABS + 4 * e + rq];
    const short8* afe = af + ((size_t)(r * 4 + e) * 32) * 64 + lane;
#pragma unroll
    for (int mi = 0; mi < 4; ++mi) {
      int mt = wm * 4 + mi;
      floatx4 acc0 = {0, 0, 0, 0}, acc1 = {0, 0, 0, 0};
#pragma unroll
      for (int kt = 0; kt < 4; ++kt) {
        short8 a = afe[(mt * 4 + kt) * 64];
        acc0 = __builtin_amdgcn_mfma_f32_16x16x32_bf16(a, bf0[kt], acc0, 0, 0, 0);
        acc1 = __builtin_amdgcn_mfma_f32_16x16x32_bf16(a, bf1[kt], acc1, 0, 0, 0);
      }
#pragma unroll
      for (int i = 0; i < 4; ++i) {
        int q = mt * 16 + quad * 4 + i;
        float fq = fvs[e][q];
        float fqm = (q > 0) ? fvs[e][q - 1] : 0.f;
        float rsv = fq * impA + fqm * impB;
        csum[mi][i] += rsv;
        float d0 = d0r[mi][i];
        float conv = d0 * acc0[i] + (1.0f - d0) * acc1[i];
        float z = (mix0r * rsv + conv) * ge;
        float e2 = __expf(2.0f * z);
        tansum[mi][i] += 1.0f - 2.0f / (e2 + 1.0f);
      }
    }
  }
#pragma unroll
  for (int mi = 0; mi < 4; ++mi)
#pragma unroll
    for (int i = 0; i < 4; ++i) {
      int q = (wm * 4 + mi) * 16 + quad * 4 + i;
      atomicAdd(&out[(size_t)rm * NS + q * 1024 + col], tansum[mi][i]);
      out[532480 + (size_t)r * NS + q * 1024 + col] = csum[mi][i];
    }
}

extern "C" void kernel_launch(void* const* d_in, const int* in_sizes, int n_in,
                              void* d_out, int out_size, void* d_ws, size_t ws_size,
                              hipStream_t stream) {
  const float* csig   = (const float*)d_in[0];
  const float* deform = (const float*)d_in[1];
  const float* aem    = (const float*)d_in[2];
  const float* aes    = (const float*)d_in[3];
  const float* aea    = (const float*)d_in[4];
  const float* aep    = (const float*)d_in[5];
  const float* aeo    = (const float*)d_in[6];
  const float* ddmp   = (const float*)d_in[7];
  const float* dmas   = (const float*)d_in[8];
  const float* dten   = (const float*)d_in[9];
  const float* ddisp  = (const float*)d_in[10];
  const float* damp   = (const float*)d_in[11];
  const float* infl   = (const float*)d_in[12];
  const float* smix   = (const float*)d_in[13];
  const float* router = (const float*)d_in[14];
  const float* lmix   = (const float*)d_in[15];
  const float* gains  = (const float*)d_in[16];
  const float* anoise = (const float*)d_in[17];

  float*  wsf = (float*)d_ws;
  unsigned short* resb = (unsigned short*)d_ws;
  unsigned short* abf  = (unsigned short*)d_ws + AFRAG_USH;
  unsigned short* abf2 = (unsigned short*)d_ws + ABF2_USH;
  unsigned short* Hb   = (unsigned short*)d_ws + HB_USH;
  float*  out = (float*)d_out;

  kA_prep<<<576, 256, 0, stream>>>(csig, deform, ddmp, dmas, dten, ddisp, damp,
                                   infl, smix, router, lmix, gains,
                                   aem, aes, aea, aep, wsf, abf2, out);
  k1_dho<<<dim3(512, 32), 256, 0, stream>>>(wsf, resb, wsf + OFF_PART);
  kB_mid<<<420, 256, 0, stream>>>(aeo, anoise, wsf, abf);
  k4_mfma<<<dim3(32, 32), 256, 0, stream>>>(resb, abf, wsf, Hb);
  k6_mfma<<<dim3(32, 16), 256, 0, stream>>>(Hb, wsf + OFF_IMP, abf2, wsf, out);
}

// Round 9
// 170.045 us; speedup vs baseline: 6.4800x; 1.0400x over previous
//
#include <hip/hip_runtime.h>
#include <math.h>

#define NS 131072
#define EPSF 1e-8f

// workspace float offsets
#define OFF_IMP    8388608u  // 16*2048
#define OFF_VG     8421376u  // 8*2048
#define OFF_DW     8437760u  // 131072 deformation ch0 weight
#define OFF_FV     8568832u  // 4*16*128 routed frames
#define OFF_NORM   8577024u  // 32 res sumsq
#define OFF_MIX0   8577064u  // 16
#define OFF_MIX1   8577080u  // 16
#define OFF_GABS   8577096u  // 16
#define OFF_PART   8578560u  // 32*512 per-block norm partials
#define OFF_GSSP   8594944u  // 8*8 gauss sumsq partials

// ushort offsets
#define AFRAG_USH  4194304u  // imp A-frags [16 r][65 sc][64 lane][8]
#define ABF2_USH   4726784u  // fv-Toeplitz A-frags [16r][4e][8mt][4kt][64][8]
#define HB_USH     8388608u  // H bf16 [32 rx][131072]

typedef __attribute__((ext_vector_type(8))) short short8;
typedef __attribute__((ext_vector_type(4))) float floatx4;
typedef __attribute__((ext_vector_type(4))) unsigned short ushort4v;

#define INV2PI 0.15915494309189535f

__device__ __forceinline__ float sigmf(float x) { return 1.0f / (1.0f + expf(-x)); }

__device__ __forceinline__ unsigned short f2bf(float x) {
  unsigned u = __float_as_uint(x);
  unsigned r = (u + 0x7FFFu + ((u >> 16) & 1u)) >> 16;
  return (unsigned short)r;
}

// ---------------- K01: blocks<512: zero out-sum, dw, fv/before, abf2, (block0: mixes/gains);
//                  blocks 512-575: gauss -> gss partials;
//                  blocks >=576: DHO chain (self-computed params) -> res bf16 + norm partials
// pf LDS layout (DHO branch): [0..6) -gam | [6..12) amp*x0 | [12..18) gam*amp*x0 |
//   [18..24) infl*ln10 | [24..26) B1p | [26..28) om1/2pi | [28..32) Wf | [33..36) w3
__global__ __launch_bounds__(256) void k01_prep_dho(
    const float* __restrict__ csig, const float* __restrict__ deform,
    const float* __restrict__ ddmp, const float* __restrict__ dmas,
    const float* __restrict__ dten, const float* __restrict__ ddisp,
    const float* __restrict__ damp, const float* __restrict__ infl,
    const float* __restrict__ smix, const float* __restrict__ router,
    const float* __restrict__ lmix, const float* __restrict__ gains,
    const float* __restrict__ means, const float* __restrict__ stds,
    const float* __restrict__ amps, const float* __restrict__ pos,
    float* __restrict__ wsf, unsigned short* __restrict__ abf2,
    unsigned short* __restrict__ resb, float* __restrict__ partials,
    float* __restrict__ out)
{
  int tid = threadIdx.x;
  int bid = blockIdx.x;
  if (bid < 512) {
    int t = bid * 256 + tid;
    { // zero the atomically-accumulated output region
      float4 z = {0.f, 0.f, 0.f, 0.f};
      *(float4*)&out[(size_t)t * 4] = z;
    }
    { // deformation softmax + interp weight ch0
      float src = (t + 0.5f) * (1.0f / 1024.0f) - 0.5f;
      src = fminf(fmaxf(src, 0.0f), 127.0f);
      int lo = (int)src;
      int hi = min(lo + 1, 127);
      float w = src - (float)lo;
      float c0l = 1.0f / (1.0f + expf(deform[128 + lo] - (1.0f + deform[lo])));
      float c0h = 1.0f / (1.0f + expf(deform[128 + hi] - (1.0f + deform[hi])));
      wsf[OFF_DW + t] = c0l * (1.0f - w) + c0h * w;
    }
    int mt = bid & 7, e = (bid >> 3) & 3, r = (bid >> 5) & 15;
    __shared__ float fvrow[128];
    if (tid < 128) {
      float s = 0.f;
      for (int c = 0; c < 16; ++c)
        s += csig[(e * 16 + c) * 128 + tid] * router[c * 16 + r];
      fvrow[tid] = s;
      if (mt == 0) {
        wsf[OFF_FV + (e * 16 + r) * 128 + tid] = s;
        out[524288 + (e * 16 + r) * 128 + tid] = s;   // 'before'
      }
    }
    __syncthreads();
    {
      int gid = bid * 256 + tid;
      int lane = gid & 63;
      int kt = (gid >> 6) & 3;
      int m = lane & 15, quad = lane >> 4;
      int base = mt * 16 + m - kt * 32 - quad * 8;
      short8 v;
#pragma unroll
      for (int j = 0; j < 8; ++j) {
        int f = base - j;
        unsigned short b = 0;
        if (f >= 0 && f < 128) b = f2bf(fvrow[f]);
        v[j] = (short)b;
      }
      *(short8*)&abf2[(size_t)gid * 8] = v;
    }
    if (bid == 0 && tid < 16) {
      int r2 = tid;
      float l0 = lmix[r2 * 2], l1 = lmix[r2 * 2 + 1];
      float mx = fmaxf(l0, l1);
      float e0 = expf(l0 - mx), e1 = expf(l1 - mx), inv = 1.0f / (e0 + e1);
      wsf[OFF_MIX0 + r2] = e0 * inv;
      wsf[OFF_MIX1 + r2] = e1 * inv;
      wsf[OFF_GABS + r2] = fabsf(gains[r2]);
    }
  } else if (bid < 576) {                // gauss: 64 blocks
    int gb = bid - 512;
    int g = gb >> 3;
    int i = (gb & 7) * 256 + tid;
    __shared__ float kS[16], rateS[16], logAS[16], aS[16];
    __shared__ int dS[16];
    __shared__ float red[4];
    if (tid < 16) {
      int c = tid, idx = c * 8 + g;
      double m = fabs((double)means[idx]);
      double s = fabs((double)stds[idx]);
      double k = m / (s + 1e-8); k = k * k;
      double rate = m / (s * s + 1e-8);
      double logA = k * log(rate + 1e-8) - lgamma(k);
      kS[c] = (float)k; rateS[c] = (float)rate; logAS[c] = (float)logA;
      aS[c] = fabsf(amps[idx]);
      int d = 0;
      for (int l = 0; l < 11; ++l) {
        float p0 = pos[(idx * 11 + l) * 2], p1 = pos[(idx * 11 + l) * 2 + 1];
        d = d * 2 + (p1 > p0 ? 1 : 0);
      }
      dS[c] = d;
    }
    __syncthreads();
    const float step = (float)((1.0 - 1e-8) / 2047.0);
    float v = 0.f;
    for (int c = 0; c < 16; ++c) {
      int mi = i - dS[c];
      if (mi >= 0) {
        float tm = 1e-8f + (float)mi * step;
        float lp = logAS[c] + (kS[c] - 1.0f) * __logf(tm) - rateS[c] * tm;
        v += aS[c] * __expf(lp);
      }
    }
    wsf[OFF_VG + g * 2048 + i] = v;
    float sumsq = v * v;
#pragma unroll
    for (int off = 32; off; off >>= 1) sumsq += __shfl_down(sumsq, off, 64);
    if ((tid & 63) == 0) red[tid >> 6] = sumsq;
    __syncthreads();
    if (tid == 0) wsf[OFF_GSSP + gb] = red[0] + red[1] + red[2] + red[3];
  } else {                               // DHO: 16384 blocks
    int b = bid - 576;
    int rx = b >> 9;
    int t = (b & 511) * 256 + tid;
    int r = rx >> 1, x = rx & 1;
    __shared__ float pf[40];             // [33..36) = stack softmax w3 (no overlap w/ Wf)
    __shared__ float bred[4];
    if (tid < 6) {
      int ent = tid, bb = ent >> 1, o = ent & 1;
      int id = ((bb * 2 + o) * 16 + r) * 2 + x;
      float mass = 2.0f * sigmf(dmas[id]);
      float gam = 30.0f * sigmf(ddmp[id]) / (2.0f * mass);
      double W = exp((double)dten[id] * 2.302585092994046) / (double)mass;
      float x0v = ddisp[id];
      float ampv = damp[id];
      float infv = 0.f;
      if (bb == 1) infv = infl[(o * 16 + r) * 2 + x];
      if (bb == 2) infv = infl[((2 + o) * 16 + r) * 2 + x];
      pf[0 + ent]  = -gam;
      pf[6 + ent]  = ampv * x0v;
      pf[12 + ent] = gam * ampv * x0v;
      pf[18 + ent] = infv * 2.3025851f;
      if (bb == 0) {
        double om = sqrt(W - (double)gam * (double)gam);
        pf[24 + o] = (float)((double)(gam * x0v * ampv) / om);
        pf[26 + o] = (float)(om * 0.15915494309189535);
      } else {
        pf[28 + ent - 2] = (float)W;
      }
    }
    if (tid == 8) {
      float a0 = smix[rx * 3], a1 = smix[rx * 3 + 1], a2 = smix[rx * 3 + 2];
      float mm = fmaxf(a0, fmaxf(a1, a2));
      float e0 = expf(a0 - mm), e1 = expf(a1 - mm), e2 = expf(a2 - mm);
      float inv = 1.0f / (e0 + e1 + e2);
      pf[33] = e0 * inv; pf[34] = e1 * inv; pf[35] = e2 * inv;
    }
    __syncthreads();
    float ttf = (float)t * (10.0f / 131071.0f);
    float o1v = 0.f;
#pragma unroll
    for (int o = 0; o < 2; ++o) {
      float fr = pf[26 + o] * ttf;
      fr -= rintf(fr);
      float sn = __builtin_amdgcn_sinf(fr);
      float cn = __builtin_amdgcn_cosf(fr);
      float ex = __expf(pf[o] * ttf);
      o1v += ex * (pf[6 + o] * cn + pf[24 + o] * sn);
    }
    float prev = o1v, o2v = 0.f, o3v = 0.f;
#pragma unroll
    for (int blk = 1; blk < 3; ++blk) {
      float acc = 0.f;
#pragma unroll
      for (int oo = 0; oo < 2; ++oo) {
        int o = blk * 2 + oo;
        float ng = pf[o];
        float p10 = __expf(prev * pf[18 + o]);
        float rad = __builtin_fmaf(pf[28 + o - 2], p10, -(ng * ng));
        float om = __builtin_amdgcn_sqrtf(rad);
        float fr = (om * INV2PI) * ttf;
        fr -= rintf(fr);
        float sn = __builtin_amdgcn_sinf(fr);
        float cn = __builtin_amdgcn_cosf(fr);
        float Bp = pf[12 + o] * __builtin_amdgcn_rcpf(om);
        float ex = __expf(ng * ttf);
        acc += ex * (pf[6 + o] * cn + Bp * sn);
      }
      if (blk == 1) o2v = acc; else o3v = acc;
      prev = acc;
    }
    float rv = pf[33] * o1v + pf[34] * o2v + pf[35] * o3v;
    resb[(size_t)rx * NS + t] = f2bf(rv);
    float sq = rv * rv;
#pragma unroll
    for (int off = 32; off; off >>= 1) sq += __shfl_down(sq, off, 64);
    if ((tid & 63) == 0) bred[tid >> 6] = sq;
    __syncthreads();
    if (tid == 0)
      partials[rx * 512 + (b & 511)] = bred[0] + bred[1] + bred[2] + bred[3];
  }
}

// ---------------- B: blocks 0-31 norm reduce; 32-159 impulse; 160-419 abf frags (imp inline)
__global__ __launch_bounds__(256) void kB_mid(
    const float* __restrict__ ovamp, const float* __restrict__ noise,
    float* __restrict__ wsf, unsigned short* __restrict__ abf)
{
  int bid = blockIdx.x;
  int tid = threadIdx.x;
  if (bid < 32) {                        // norm reduce
    int rx = bid;
    const float* partials = wsf + OFF_PART;
    __shared__ float red[4];
    float s = partials[rx * 512 + tid] + partials[rx * 512 + 256 + tid];
#pragma unroll
    for (int off = 32; off; off >>= 1) s += __shfl_down(s, off, 64);
    if ((tid & 63) == 0) red[tid >> 6] = s;
    __syncthreads();
    if (tid == 0) wsf[OFF_NORM + rx] = red[0] + red[1] + red[2] + red[3];
    return;
  }
  __shared__ float wS[8];
  if (tid < 8) {
    float g8 = 0.f;
#pragma unroll
    for (int u = 0; u < 8; ++u) g8 += wsf[OFF_GSSP + tid * 8 + u];
    wS[tid] = 1.0f / (sqrtf(g8) + EPSF);
  }
  __syncthreads();
  const float* vg = wsf + OFF_VG;
  if (bid < 160) {                       // impulse
    int idx0 = bid - 32;
    int c = idx0 >> 3;
    int i = (idx0 & 7) * 256 + tid;
    float S = 0.f;
#pragma unroll
    for (int g = 0; g < 8; ++g) S += vg[g * 2048 + i] * wS[g];
    wsf[OFF_IMP + c * 2048 + i] = ovamp[c] * S * noise[c * 2048 + i];
    return;
  }
  // abf: imp recomputed inline
  int gid = (bid - 160) * 256 + tid;     // 16*65*64 = 66560
  if (gid >= 66560) return;
  int r = gid / (65 * 64);
  int rem = gid % (65 * 64);
  int sc = rem >> 6, lane = rem & 63;
  int m = lane & 15, quad = lane >> 4;
  int qp = (quad < 2) ? quad : quad - 4;
  int base = 32 * sc + m - 8 * qp;
  float oa = ovamp[r];
  short8 v;
#pragma unroll
  for (int j = 0; j < 8; ++j) {
    int idx = base - j;
    unsigned short b = 0;
    if (idx >= 0 && idx < 2048) {
      float S = 0.f;
#pragma unroll
      for (int g = 0; g < 8; ++g) S += vg[g * 2048 + idx] * wS[g];
      b = f2bf(oa * S * noise[r * 2048 + idx]);
    }
    v[j] = (short)b;
  }
  *(short8*)&abf[(size_t)gid * 8] = v;
}

// ---------------- K4: H via MFMA block-Toeplitz, rolling B-frag window; H stored bf16
__global__ __launch_bounds__(256) void k4_mfma(
    const unsigned short* __restrict__ resb, const unsigned short* __restrict__ abf,
    const float* __restrict__ wsf, unsigned short* __restrict__ Hb)
{
  int rx = blockIdx.y, r = rx >> 1;
  int n0 = blockIdx.x * 256;                       // 256 columns of 16 samples
  __shared__ __align__(16) unsigned short Xs[9280]; // 386 cols x stride 24
  int tid = threadIdx.x;
  for (int i = tid; i < 772; i += 256) {           // 16B chunks
    int q_rel = i >> 1, p8 = (i & 1) * 8;
    int q = n0 - 130 + q_rel;
    short8 v = {0, 0, 0, 0, 0, 0, 0, 0};
    if (q >= 0) v = *(const short8*)&resb[(size_t)rx * NS + q * 16 + p8];
    *(short8*)&Xs[q_rel * 24 + p8] = v;
  }
  __syncthreads();
  int lane = tid & 63, w = tid >> 6;
  int quad = lane >> 4, nl = lane & 15;
  float n1 = sqrtf(wsf[OFF_NORM + rx]);
  float s1 = 1.0f / (n1 + EPSF);
  float scale = s1 * (1.0f / (n1 * s1 + EPSF)) * wsf[OFF_MIX1 + r];
  const short8* af = (const short8*)(abf) + (size_t)r * 65 * 64 + lane;
  floatx4 acc0 = {0,0,0,0}, acc1 = {0,0,0,0}, acc2 = {0,0,0,0}, acc3 = {0,0,0,0};
  const char* xbase = (const char*)Xs + (size_t)(130 + w * 64 + nl - (quad >> 1)) * 48
                      + (quad & 1) * 16;
  short8 wbuf[25];
#pragma unroll
  for (int s = -24; s < 0; ++s)
    wbuf[s + 25] = *(const short8*)(xbase - 96 * s);
#pragma unroll
  for (int sc = 0; sc < 65; ++sc) {
    wbuf[sc % 25] = *(const short8*)(xbase - 96 * sc);
    short8 a = af[sc * 64];
    acc0 = __builtin_amdgcn_mfma_f32_16x16x32_bf16(a, wbuf[sc % 25],        acc0, 0, 0, 0);
    acc1 = __builtin_amdgcn_mfma_f32_16x16x32_bf16(a, wbuf[(sc + 17) % 25], acc1, 0, 0, 0);
    acc2 = __builtin_amdgcn_mfma_f32_16x16x32_bf16(a, wbuf[(sc + 9) % 25],  acc2, 0, 0, 0);
    acc3 = __builtin_amdgcn_mfma_f32_16x16x32_bf16(a, wbuf[(sc + 1) % 25],  acc3, 0, 0, 0);
  }
  unsigned short* hp = Hb + (size_t)rx * NS + 16 * (n0 + w * 64 + nl) + quad * 4;
  ushort4v h0, h1, h2, h3;
#pragma unroll
  for (int i = 0; i < 4; ++i) {
    h0[i] = f2bf(acc0[i] * scale);
    h1[i] = f2bf(acc1[i] * scale);
    h2[i] = f2bf(acc2[i] * scale);
    h3[i] = f2bf(acc3[i] * scale);
  }
  *(ushort4v*)(hp)       = h0;
  *(ushort4v*)(hp + 256) = h1;
  *(ushort4v*)(hp + 512) = h2;
  *(ushort4v*)(hp + 768) = h3;
}

// ---------------- K6: 128-tap stride conv via MFMA + deform mix + tanh reduce + cs
__global__ __launch_bounds__(256) void k6_mfma(
    const unsigned short* __restrict__ Hb, const float* __restrict__ imp,
    const unsigned short* __restrict__ abf2,
    const float* __restrict__ wsf, float* __restrict__ out)
{
  int r = blockIdx.y;
  int n0 = blockIdx.x * 32;
  int rm = r & 3, rq = r >> 2;
  int tid = threadIdx.x;
  int w = tid >> 6, lane = tid & 63;
  int wc = w & 1, wm = w >> 1;
  int quad = lane >> 4, n = lane & 15;
  int col = n0 + wc * 16 + n;              // t' in [0,1024)

  __shared__ float fvs[4][128];
  for (int i = tid; i < 512; i += 256)
    fvs[i >> 7][i & 127] = wsf[OFF_FV + ((i >> 7) * 16 + r) * 128 + (i & 127)];
  __syncthreads();

  short8 bf0[4], bf1[4];
  const unsigned short* H0 = Hb + (size_t)(2 * r) * NS + col;
  const unsigned short* H1 = Hb + (size_t)(2 * r + 1) * NS + col;
#pragma unroll
  for (int kt = 0; kt < 4; ++kt) {
#pragma unroll
    for (int j = 0; j < 8; ++j) {
      int p = kt * 32 + quad * 8 + j;
      bf0[kt][j] = (short)H0[(size_t)p * 1024];
      bf1[kt][j] = (short)H1[(size_t)p * 1024];
    }
  }

  float d0r[4][4];
  const float* dwg = wsf + OFF_DW;
#pragma unroll
  for (int mi = 0; mi < 4; ++mi)
#pragma unroll
    for (int i = 0; i < 4; ++i) {
      int q = (wm * 4 + mi) * 16 + quad * 4 + i;
      d0r[mi][i] = dwg[q * 1024 + col];
    }

  float impA = imp[r * 2048 + col];
  float impB = imp[r * 2048 + 1024 + col];
  float mix0r = wsf[OFF_MIX0 + r];

  float tansum[4][4], csum[4][4];
#pragma unroll
  for (int mi = 0; mi < 4; ++mi)
#pragma unroll
    for (int i = 0; i < 4; ++i) { tansum[mi][i] = 0.f; csum[mi][i] = 0.f; }

  const short8* af = (const short8*)abf2;
  for (int e = 0; e < 4; ++e) {
    float ge = wsf[OFF_GABS + 4 * e + rq];
    const short8* afe = af + ((size_t)(r * 4 + e) * 32) * 64 + lane;
#pragma unroll
    for (int mi = 0; mi < 4; ++mi) {
      int mt = wm * 4 + mi;
      floatx4 acc0 = {0, 0, 0, 0}, acc1 = {0, 0, 0, 0};
#pragma unroll
      for (int kt = 0; kt < 4; ++kt) {
        short8 a = afe[(mt * 4 + kt) * 64];
        acc0 = __builtin_amdgcn_mfma_f32_16x16x32_bf16(a, bf0[kt], acc0, 0, 0, 0);
        acc1 = __builtin_amdgcn_mfma_f32_16x16x32_bf16(a, bf1[kt], acc1, 0, 0, 0);
      }
#pragma unroll
      for (int i = 0; i < 4; ++i) {
        int q = mt * 16 + quad * 4 + i;
        float fq = fvs[e][q];
        float fqm = (q > 0) ? fvs[e][q - 1] : 0.f;
        float rsv = fq * impA + fqm * impB;
        csum[mi][i] += rsv;
        float d0 = d0r[mi][i];
        float conv = d0 * acc0[i] + (1.0f - d0) * acc1[i];
        float z = (mix0r * rsv + conv) * ge;
        float e2 = __expf(2.0f * z);
        tansum[mi][i] += 1.0f - 2.0f * __builtin_amdgcn_rcpf(e2 + 1.0f);
      }
    }
  }
#pragma unroll
  for (int mi = 0; mi < 4; ++mi)
#pragma unroll
    for (int i = 0; i < 4; ++i) {
      int q = (wm * 4 + mi) * 16 + quad * 4 + i;
      atomicAdd(&out[(size_t)rm * NS + q * 1024 + col], tansum[mi][i]);
      out[532480 + (size_t)r * NS + q * 1024 + col] = csum[mi][i];
    }
}

extern "C" void kernel_launch(void* const* d_in, const int* in_sizes, int n_in,
                              void* d_out, int out_size, void* d_ws, size_t ws_size,
                              hipStream_t stream) {
  const float* csig   = (const float*)d_in[0];
  const float* deform = (const float*)d_in[1];
  const float* aem    = (const float*)d_in[2];
  const float* aes    = (const float*)d_in[3];
  const float* aea    = (const float*)d_in[4];
  const float* aep    = (const float*)d_in[5];
  const float* aeo    = (const float*)d_in[6];
  const float* ddmp   = (const float*)d_in[7];
  const float* dmas   = (const float*)d_in[8];
  const float* dten   = (const float*)d_in[9];
  const float* ddisp  = (const float*)d_in[10];
  const float* damp   = (const float*)d_in[11];
  const float* infl   = (const float*)d_in[12];
  const float* smix   = (const float*)d_in[13];
  const float* router = (const float*)d_in[14];
  const float* lmix   = (const float*)d_in[15];
  const float* gains  = (const float*)d_in[16];
  const float* anoise = (const float*)d_in[17];

  float*  wsf = (float*)d_ws;
  unsigned short* resb = (unsigned short*)d_ws;
  unsigned short* abf  = (unsigned short*)d_ws + AFRAG_USH;
  unsigned short* abf2 = (unsigned short*)d_ws + ABF2_USH;
  unsigned short* Hb   = (unsigned short*)d_ws + HB_USH;
  float*  out = (float*)d_out;

  k01_prep_dho<<<16960, 256, 0, stream>>>(csig, deform, ddmp, dmas, dten, ddisp,
                                          damp, infl, smix, router, lmix, gains,
                                          aem, aes, aea, aep, wsf, abf2, resb,
                                          wsf + OFF_PART, out);
  kB_mid<<<420, 256, 0, stream>>>(aeo, anoise, wsf, abf);
  k4_mfma<<<dim3(32, 32), 256, 0, stream>>>(resb, abf, wsf, Hb);
  k6_mfma<<<dim3(32, 16), 256, 0, stream>>>(Hb, wsf + OFF_IMP, abf2, wsf, out);
}